// Round 2
// baseline (17643.140 us; speedup 1.0000x reference)
//
#include <hip/hip_runtime.h>
#include <hip/hip_bf16.h>
#include <math.h>

#define MTOK 16384      // B*L tokens
#define DM   768
#define DI   1536
#define DS   16
#define RNK  48
#define LSEQ 2048
#define NBATCH 8
#define EPSV 1e-5f

typedef __hip_bfloat16 bf16;

__device__ __forceinline__ float b2f(bf16 v){ return __bfloat162float(v); }
__device__ __forceinline__ bf16  f2b(float v){ return __float2bfloat16(v); }
__device__ __forceinline__ float silu_f(float x){ return x / (1.f + expf(-x)); }

// ---------------- fp32 -> bf16 convert (residual init) ----------------
__global__ __launch_bounds__(256) void cvt_kernel(
    const float* __restrict__ x, bf16* __restrict__ h, int n)
{
    int i = blockIdx.x * 256 + threadIdx.x;
    if (i < n) h[i] = f2b(x[i]);
}

// ---------------- RMSNorm over 768 (3 elems/thread) ----------------
__global__ __launch_bounds__(256) void rmsnorm_kernel(
    const bf16* __restrict__ in, const float* __restrict__ w,
    bf16* __restrict__ out, float* __restrict__ rs_out)
{
    int row = blockIdx.x;
    const bf16* r = in + (size_t)row * DM;
    float v0 = b2f(r[threadIdx.x]);
    float v1 = b2f(r[threadIdx.x + 256]);
    float v2 = b2f(r[threadIdx.x + 512]);
    float s = v0*v0 + v1*v1 + v2*v2;
    for (int o = 32; o > 0; o >>= 1) s += __shfl_down(s, o, 64);
    __shared__ float red[4];
    if ((threadIdx.x & 63) == 0) red[threadIdx.x >> 6] = s;
    __syncthreads();
    float rs = rsqrtf((red[0]+red[1]+red[2]+red[3]) * (1.f/DM) + EPSV);
    if (rs_out && threadIdx.x == 0) rs_out[row] = rs;
    if (out) {
        out[(size_t)row*DM + threadIdx.x]       = f2b(v0 * rs * w[threadIdx.x]);
        out[(size_t)row*DM + threadIdx.x + 256] = f2b(v1 * rs * w[threadIdx.x + 256]);
        out[(size_t)row*DM + threadIdx.x + 512] = f2b(v2 * rs * w[threadIdx.x + 512]);
    }
}

// ---------------- GEMM: C[M,N] (+)= A[M,K] @ W[N,K]^T ----------------
// A bf16 (CONVA=1: A-tile = silu(causal dwconv4(A)) on the fly), W fp32.
// mode 0: C = acc ; mode 2: C += acc ; mode 3: C = C * silu(acc)  (gating)
template<int CONVA>
__global__ __launch_bounds__(256) void gemm_kernel(
    const bf16* __restrict__ A, int lda,
    const float* __restrict__ W, int ldw,
    bf16* __restrict__ C, int ldc,
    int M, int N, int K,
    const float* __restrict__ cw, const float* __restrict__ cb,
    int mode)
{
    __shared__ float As[16][68];
    __shared__ float Ws[16][68];
    int bm = blockIdx.y * 64;
    int bn = blockIdx.x * 64;
    int tid = threadIdx.x;
    int tm = (tid >> 4) * 4;
    int tn = (tid & 15) * 4;
    float acc[4][4] = {};
    for (int k0 = 0; k0 < K; k0 += 16) {
        #pragma unroll
        for (int i = 0; i < 4; i++) {
            int idx = tid + i * 256;        // 0..1023
            int r = idx >> 4;               // 0..63
            int kk = idx & 15;
            int m = bm + r;
            int c = k0 + kk;
            float av;
            if (CONVA) {
                int t = m & (LSEQ - 1);
                float a = cb[c];
                #pragma unroll
                for (int j = 0; j < 4; j++) {
                    int tt = t - 3 + j;
                    if (tt >= 0) a += cw[c*4 + j] * b2f(A[(size_t)(m-3+j)*lda + c]);
                }
                av = silu_f(a);
            } else {
                av = b2f(A[(size_t)m * lda + c]);
            }
            As[kk][r] = av;
            float wv = 0.f;
            if (bn + r < N) wv = W[(size_t)(bn + r) * ldw + c];
            Ws[kk][r] = wv;
        }
        __syncthreads();
        #pragma unroll
        for (int kk = 0; kk < 16; kk++) {
            float4 a4 = *(const float4*)&As[kk][tm];
            float4 w4 = *(const float4*)&Ws[kk][tn];
            acc[0][0] += a4.x*w4.x; acc[0][1] += a4.x*w4.y; acc[0][2] += a4.x*w4.z; acc[0][3] += a4.x*w4.w;
            acc[1][0] += a4.y*w4.x; acc[1][1] += a4.y*w4.y; acc[1][2] += a4.y*w4.z; acc[1][3] += a4.y*w4.w;
            acc[2][0] += a4.z*w4.x; acc[2][1] += a4.z*w4.y; acc[2][2] += a4.z*w4.z; acc[2][3] += a4.z*w4.w;
            acc[3][0] += a4.w*w4.x; acc[3][1] += a4.w*w4.y; acc[3][2] += a4.w*w4.z; acc[3][3] += a4.w*w4.w;
        }
        __syncthreads();
    }
    #pragma unroll
    for (int i = 0; i < 4; i++) {
        size_t m = bm + tm + i;
        #pragma unroll
        for (int j = 0; j < 4; j++) {
            int n = bn + tn + j;
            if (n < N) {
                size_t off = m * (size_t)ldc + n;
                float v = acc[i][j];
                if (mode == 2)      C[off] = f2b(b2f(C[off]) + v);
                else if (mode == 3) C[off] = f2b(b2f(C[off]) * silu_f(v));
                else                C[off] = f2b(v);
            }
        }
    }
}

// ---------------- selective scan: fused conv4+silu, dt_proj+softplus ----------------
// 16 lanes per (b,e) group. Reads xin from xy, writes y in place.
__global__ __launch_bounds__(256) void scan_kernel(
    bf16* __restrict__ xy,            // [M,1536]: xin -> y
    const bf16* __restrict__ dbc,     // [M,80]: dt_r | B | C
    const float* __restrict__ A_log,  // [1536,16] layer slice
    const float* __restrict__ Dp,     // [1536]
    const float* __restrict__ dtw,    // [1536,48]
    const float* __restrict__ dtb,    // [1536]
    const float* __restrict__ cw,     // [1536,4]
    const float* __restrict__ cb)     // [1536]
{
    int g = blockIdx.x * 16 + (threadIdx.x >> 4);
    int lane = threadIdx.x & 15;
    int b = g / DI, e = g - b * DI;
    float a    = -expf(A_log[e * DS + lane]);
    float dp   = Dp[e];
    float dtbe = dtb[e];
    float w0 = dtw[e*RNK + lane*3 + 0];
    float w1 = dtw[e*RNK + lane*3 + 1];
    float w2 = dtw[e*RNK + lane*3 + 2];
    float c0 = cw[e*4+0], c1 = cw[e*4+1], c2 = cw[e*4+2], c3 = cw[e*4+3];
    float cbe = cb[e];
    bf16* xrow = xy + (size_t)b * LSEQ * DI + e;
    const bf16* drow = dbc + (size_t)b * LSEQ * 80;
    float h = 0.f;
    float p0 = 0.f, p1 = 0.f, p2 = 0.f;   // xin[t-3], xin[t-2], xin[t-1]
    for (int t = 0; t < LSEQ; t++) {
        float xt = b2f(xrow[(size_t)t * DI]);
        float xv = silu_f(cbe + c0*p0 + c1*p1 + c2*p2 + c3*xt);
        p0 = p1; p1 = p2; p2 = xt;
        const bf16* dr = drow + (size_t)t * 80;
        float pd = w0*b2f(dr[lane*3]) + w1*b2f(dr[lane*3+1]) + w2*b2f(dr[lane*3+2]);
        pd += __shfl_xor(pd, 1, 16);
        pd += __shfl_xor(pd, 2, 16);
        pd += __shfl_xor(pd, 4, 16);
        pd += __shfl_xor(pd, 8, 16);
        float draw = pd + dtbe;
        float d = (draw > 20.f) ? draw : log1pf(expf(draw));
        float Bv = b2f(dr[48 + lane]);
        float Cv = b2f(dr[64 + lane]);
        h = expf(d * a) * h + (d * xv) * Bv;
        float p = h * Cv;
        p += __shfl_xor(p, 1, 16);
        p += __shfl_xor(p, 2, 16);
        p += __shfl_xor(p, 4, 16);
        p += __shfl_xor(p, 8, 16);
        if (lane == 0) xrow[(size_t)t * DI] = f2b(p + xv * dp);
    }
}

// ---------------- pooled[b,d] = (1/L) sum_t h[b,t,d]*rs[b,t]*wf[d] ----------------
__global__ __launch_bounds__(128) void pool_kernel(
    const bf16* __restrict__ h, const float* __restrict__ rs,
    const float* __restrict__ wf, float* __restrict__ pooled)
{
    int b = blockIdx.x, dc = blockIdx.y, tc = blockIdx.z;
    int d = dc * 128 + threadIdx.x;
    float s = 0.f;
    int t0 = tc * 128;
    for (int t = t0; t < t0 + 128; t++) {
        int row = b * LSEQ + t;
        s += b2f(h[(size_t)row * DM + d]) * rs[row];
    }
    atomicAdd(&pooled[b * DM + d], s * wf[d] * (1.f / LSEQ));
}

// ---------------- classifier head + log_softmax + NLL ----------------
__global__ __launch_bounds__(128) void head_kernel(
    const float* __restrict__ pooled, const float* __restrict__ cls_w,
    const float* __restrict__ cls_b, const int* __restrict__ labels,
    float* __restrict__ out)
{
    __shared__ float lg[80];
    int tid = threadIdx.x;
    if (tid < 80) {
        int b = tid / 10, c = tid % 10;
        float s = cls_b[c];
        for (int d = 0; d < DM; d++) s += pooled[b * DM + d] * cls_w[c * DM + d];
        lg[tid] = s;
    }
    __syncthreads();
    if (tid == 0) {
        float loss = 0.f;
        for (int b = 0; b < NBATCH; b++) {
            float mx = -1e30f;
            for (int c = 0; c < 10; c++) mx = fmaxf(mx, lg[b*10+c]);
            float se = 0.f;
            for (int c = 0; c < 10; c++) se += expf(lg[b*10+c] - mx);
            float lse = mx + logf(se);
            loss -= (lg[b*10 + labels[b]] - lse);
            for (int c = 0; c < 10; c++) out[b*10+c] = lg[b*10+c];
        }
        out[80] = loss / NBATCH;
    }
}

extern "C" void kernel_launch(void* const* d_in, const int* in_sizes, int n_in,
                              void* d_out, int out_size, void* d_ws, size_t ws_size,
                              hipStream_t stream) {
    const float* x          = (const float*)d_in[0];
    const int*   labels     = (const int*)d_in[1];
    const float* in_proj_w  = (const float*)d_in[2];
    const float* conv_w     = (const float*)d_in[3];
    const float* conv_b     = (const float*)d_in[4];
    const float* x_proj_w   = (const float*)d_in[5];
    const float* dt_w       = (const float*)d_in[6];
    const float* dt_b       = (const float*)d_in[7];
    const float* A_log      = (const float*)d_in[8];
    const float* D_param    = (const float*)d_in[9];
    const float* out_proj_w = (const float*)d_in[10];
    const float* norm_w     = (const float*)d_in[11];
    const float* normf_w    = (const float*)d_in[12];
    const float* cls_w      = (const float*)d_in[13];
    const float* cls_b      = (const float*)d_in[14];
    float* out = (float*)d_out;

    // workspace layout (~99 MB total)
    char* p = (char*)d_ws;
    bf16* h   = (bf16*)p;                 p += (size_t)MTOK * DM * 2;    // 25.2 MB
    bf16* xn  = (bf16*)p;                 p += (size_t)MTOK * DM * 2;    // 25.2 MB
    bf16* xy  = (bf16*)p;                 p += (size_t)MTOK * DI * 2;    // 50.3 MB (xin -> y -> gated)
    bf16* dbc = (bf16*)p;                 p += (size_t)MTOK * 80 * 2;    // 2.6 MB
    float* rsb    = (float*)p;            p += (size_t)MTOK * 4;
    float* pooled = (float*)p;            p += NBATCH * DM * 4;

    cvt_kernel<<<(MTOK * DM) / 256, 256, 0, stream>>>(x, h, MTOK * DM);
    hipMemsetAsync(pooled, 0, NBATCH * DM * sizeof(float), stream);

    for (int l = 0; l < 4; l++) {
        const float* inw = in_proj_w + (size_t)l * 2 * DI * DM;
        const float* cwl = conv_w + (size_t)l * DI * 4;
        const float* cbl = conv_b + (size_t)l * DI;
        const float* xwl = x_proj_w + (size_t)l * (RNK + 2*DS) * DI;
        const float* dwl = dt_w + (size_t)l * DI * RNK;
        const float* dbl = dt_b + (size_t)l * DI;
        const float* All = A_log + (size_t)l * DI * DS;
        const float* Dpl = D_param + (size_t)l * DI;
        const float* owl = out_proj_w + (size_t)l * DM * DI;

        rmsnorm_kernel<<<MTOK, 256, 0, stream>>>(h, norm_w + (size_t)l * DM, xn, nullptr);

        // xin = xn @ in_w[0:1536]^T
        gemm_kernel<0><<<dim3(DI/64, MTOK/64), 256, 0, stream>>>(
            xn, DM, inw, DM, xy, DI, MTOK, DI, DM, nullptr, nullptr, 0);

        // dbc = silu(conv(xin)) @ xw^T   (conv fused into A-loader)
        gemm_kernel<1><<<dim3(2, MTOK/64), 256, 0, stream>>>(
            xy, DI, xwl, DI, dbc, 80, MTOK, 80, DI, cwl, cbl, 0);

        // selective scan (conv + dt_proj + softplus fused); y overwrites xin
        scan_kernel<<<(NBATCH * DI) / 16, 256, 0, stream>>>(
            xy, dbc, All, Dpl, dwl, dbl, cwl, cbl);

        // gating: y *= silu(xn @ in_w[1536:3072]^T)
        gemm_kernel<0><<<dim3(DI/64, MTOK/64), 256, 0, stream>>>(
            xn, DM, inw + (size_t)DI * DM, DM, xy, DI, MTOK, DI, DM, nullptr, nullptr, 3);

        // h += y @ out_w^T
        gemm_kernel<0><<<dim3(DM/64, MTOK/64), 256, 0, stream>>>(
            xy, DI, owl, DI, h, DM, MTOK, DM, DI, nullptr, nullptr, 2);
    }

    rmsnorm_kernel<<<MTOK, 256, 0, stream>>>(h, normf_w, nullptr, rsb);
    pool_kernel<<<dim3(NBATCH, DM/128, LSEQ/128), 128, 0, stream>>>(h, rsb, normf_w, pooled);
    head_kernel<<<1, 128, 0, stream>>>(pooled, cls_w, cls_b, labels, out);
}

// Round 3
// 8167.808 us; speedup vs baseline: 2.1601x; 2.1601x over previous
//
#include <hip/hip_runtime.h>
#include <hip/hip_bf16.h>
#include <math.h>

#define MTOK 16384      // B*L tokens
#define DM   768
#define DI   1536
#define DS   16
#define RNK  48
#define LSEQ 2048
#define NBATCH 8
#define EPSV 1e-5f
#define CHK  16         // time chunks for the scan
#define CLEN (LSEQ / CHK)

typedef __hip_bfloat16 bf16;

__device__ __forceinline__ float b2f(bf16 v){ return __bfloat162float(v); }
__device__ __forceinline__ bf16  f2b(float v){ return __float2bfloat16(v); }
__device__ __forceinline__ float u2f(unsigned short u){
    union { unsigned int i; float f; } v; v.i = ((unsigned int)u) << 16; return v.f;
}
__device__ __forceinline__ float silu_f(float x){
    return x * __builtin_amdgcn_rcpf(1.f + __expf(-x));
}

// ---------------- fp32 -> bf16 convert (residual init) ----------------
__global__ __launch_bounds__(256) void cvt_kernel(
    const float* __restrict__ x, bf16* __restrict__ h, int n)
{
    int i = blockIdx.x * 256 + threadIdx.x;
    if (i < n) h[i] = f2b(x[i]);
}

// ---------------- RMSNorm over 768 (3 elems/thread) ----------------
__global__ __launch_bounds__(256) void rmsnorm_kernel(
    const bf16* __restrict__ in, const float* __restrict__ w,
    bf16* __restrict__ out, float* __restrict__ rs_out)
{
    int row = blockIdx.x;
    const bf16* r = in + (size_t)row * DM;
    float v0 = b2f(r[threadIdx.x]);
    float v1 = b2f(r[threadIdx.x + 256]);
    float v2 = b2f(r[threadIdx.x + 512]);
    float s = v0*v0 + v1*v1 + v2*v2;
    for (int o = 32; o > 0; o >>= 1) s += __shfl_down(s, o, 64);
    __shared__ float red[4];
    if ((threadIdx.x & 63) == 0) red[threadIdx.x >> 6] = s;
    __syncthreads();
    float rs = rsqrtf((red[0]+red[1]+red[2]+red[3]) * (1.f/DM) + EPSV);
    if (rs_out && threadIdx.x == 0) rs_out[row] = rs;
    if (out) {
        out[(size_t)row*DM + threadIdx.x]       = f2b(v0 * rs * w[threadIdx.x]);
        out[(size_t)row*DM + threadIdx.x + 256] = f2b(v1 * rs * w[threadIdx.x + 256]);
        out[(size_t)row*DM + threadIdx.x + 512] = f2b(v2 * rs * w[threadIdx.x + 512]);
    }
}

// ---------------- GEMM: C[M,N] (+)= A[M,K] @ W[N,K]^T ----------------
// A bf16 (CONVA=1: A-tile = silu(causal dwconv4(A)) on the fly), W fp32.
// mode 0: C = acc ; mode 2: C += acc ; mode 3: C = C * silu(acc)  (gating)
template<int CONVA>
__global__ __launch_bounds__(256) void gemm_kernel(
    const bf16* __restrict__ A, int lda,
    const float* __restrict__ W, int ldw,
    bf16* __restrict__ C, int ldc,
    int M, int N, int K,
    const float* __restrict__ cw, const float* __restrict__ cb,
    int mode)
{
    __shared__ float As[16][68];
    __shared__ float Ws[16][68];
    int bm = blockIdx.y * 64;
    int bn = blockIdx.x * 64;
    int tid = threadIdx.x;
    int tm = (tid >> 4) * 4;
    int tn = (tid & 15) * 4;
    float acc[4][4] = {};
    for (int k0 = 0; k0 < K; k0 += 16) {
        #pragma unroll
        for (int i = 0; i < 4; i++) {
            int idx = tid + i * 256;        // 0..1023
            int r = idx >> 4;               // 0..63
            int kk = idx & 15;
            int m = bm + r;
            int c = k0 + kk;
            float av;
            if (CONVA) {
                int t = m & (LSEQ - 1);
                float a = cb[c];
                #pragma unroll
                for (int j = 0; j < 4; j++) {
                    int tt = t - 3 + j;
                    if (tt >= 0) a += cw[c*4 + j] * b2f(A[(size_t)(m-3+j)*lda + c]);
                }
                av = silu_f(a);
            } else {
                av = b2f(A[(size_t)m * lda + c]);
            }
            As[kk][r] = av;
            float wv = 0.f;
            if (bn + r < N) wv = W[(size_t)(bn + r) * ldw + c];
            Ws[kk][r] = wv;
        }
        __syncthreads();
        #pragma unroll
        for (int kk = 0; kk < 16; kk++) {
            float4 a4 = *(const float4*)&As[kk][tm];
            float4 w4 = *(const float4*)&Ws[kk][tn];
            acc[0][0] += a4.x*w4.x; acc[0][1] += a4.x*w4.y; acc[0][2] += a4.x*w4.z; acc[0][3] += a4.x*w4.w;
            acc[1][0] += a4.y*w4.x; acc[1][1] += a4.y*w4.y; acc[1][2] += a4.y*w4.z; acc[1][3] += a4.y*w4.w;
            acc[2][0] += a4.z*w4.x; acc[2][1] += a4.z*w4.y; acc[2][2] += a4.z*w4.z; acc[2][3] += a4.z*w4.w;
            acc[3][0] += a4.w*w4.x; acc[3][1] += a4.w*w4.y; acc[3][2] += a4.w*w4.z; acc[3][3] += a4.w*w4.w;
        }
        __syncthreads();
    }
    #pragma unroll
    for (int i = 0; i < 4; i++) {
        size_t m = bm + tm + i;
        #pragma unroll
        for (int j = 0; j < 4; j++) {
            int n = bn + tn + j;
            if (n < N) {
                size_t off = m * (size_t)ldc + n;
                float v = acc[i][j];
                if (mode == 2)      C[off] = f2b(b2f(C[off]) + v);
                else if (mode == 3) C[off] = f2b(b2f(C[off]) * silu_f(v));
                else                C[off] = f2b(v);
            }
        }
    }
}

// ---------------- chunked selective scan, no shuffles ----------------
// One thread per (b, e, chunk); all 16 states in registers.
// PASS 1: h from 0, emit h_end[16], S=sum(d), conv boundary xin values.
// PASS 2: h from combined h_in, emit y in place over xin.
template<int PASS>
__global__ __launch_bounds__(256) void scan_pass_kernel(
    bf16* __restrict__ xy,              // [M,1536]  xin (PASS2: y overwrites)
    const bf16* __restrict__ dbc,       // [M,80]  dt_r | B | C
    const float* __restrict__ A_log,    // [1536,16] layer slice
    const float* __restrict__ Dp,       // [1536]
    const float* __restrict__ dtw,      // [1536,48]
    const float* __restrict__ dtb,      // [1536]
    const float* __restrict__ cw,       // [1536,4]
    const float* __restrict__ cb,       // [1536]
    float* __restrict__ hst,            // [B*DI, CHK, 16]
    float* __restrict__ Ssum,           // [B*DI, CHK]
    unsigned short* __restrict__ bound) // [B*DI, CHK, 4]
{
    int e = (blockIdx.x % (DI/256)) * 256 + threadIdx.x;
    int b = (blockIdx.x / (DI/256)) & (NBATCH - 1);
    int c = blockIdx.x / ((DI/256) * NBATCH);
    int t0 = c * CLEN;

    float w[RNK];
    #pragma unroll
    for (int r = 0; r < RNK; r++) w[r] = dtw[e*RNK + r];
    float a[DS];
    #pragma unroll
    for (int n = 0; n < DS; n++) a[n] = -__expf(A_log[e*DS + n]);
    float c0 = cw[e*4+0], c1 = cw[e*4+1], c2 = cw[e*4+2], c3 = cw[e*4+3];
    float cbe = cb[e], dtbe = dtb[e], dpe = Dp[e];

    size_t sidx = ((size_t)(b*DI) + e) * CHK + c;
    float hh[DS];
    if (PASS == 1) {
        #pragma unroll
        for (int n = 0; n < DS; n++) hh[n] = 0.f;
    } else {
        #pragma unroll
        for (int n = 0; n < DS; n++) hh[n] = hst[sidx*DS + n];
    }

    unsigned short* xrow = (unsigned short*)(xy + ((size_t)(b*LSEQ) + t0) * DI + e);
    const unsigned short* drow = (const unsigned short*)(dbc + ((size_t)(b*LSEQ) + t0) * 80);

    // conv rolling window warm-up (raw bf16 bits)
    unsigned short r0, r1, r2;
    if (PASS == 1) {
        if (c == 0) { r0 = 0; r1 = 0; r2 = 0; }
        else {
            r0 = xrow[-(ptrdiff_t)3*DI];
            r1 = xrow[-(ptrdiff_t)2*DI];
            r2 = xrow[-(ptrdiff_t)1*DI];
        }
        bound[sidx*4+0] = r0; bound[sidx*4+1] = r1; bound[sidx*4+2] = r2;
    } else {
        r0 = bound[sidx*4+0]; r1 = bound[sidx*4+1]; r2 = bound[sidx*4+2];
    }
    float p0 = u2f(r0), p1 = u2f(r1), p2 = u2f(r2);

    float S = 0.f;
    for (int t = 0; t < CLEN; t++) {
        float xt = u2f(xrow[(size_t)t * DI]);
        float xv = silu_f(cbe + c0*p0 + c1*p1 + c2*p2 + c3*xt);
        p0 = p1; p1 = p2; p2 = xt;

        // wave-uniform row of 80 bf16: copy to regs as 10 dwordx4-sized pieces
        uint4 q[5];
        const uint4* d4 = (const uint4*)(drow + (size_t)t * 80);
        #pragma unroll
        for (int i = 0; i < 5; i++) q[i] = d4[i];           // 80 bytes: dt_r + B
        uint4 q2[5];
        #pragma unroll
        for (int i = 0; i < 5; i++) q2[i] = d4[5 + i];      // remaining 80 bytes
        const unsigned short* ds = (const unsigned short*)q;   // [0..63]
        const unsigned short* ds2 = (const unsigned short*)q2; // [64..79] at ds2[0..15]

        float acc = dtbe;
        #pragma unroll
        for (int r = 0; r < RNK; r++) acc += w[r] * u2f(ds[r]);
        float d = (acc > 20.f) ? acc : __logf(1.f + __expf(acc));
        float dx = d * xv;
        #pragma unroll
        for (int n = 0; n < DS; n++)
            hh[n] = __expf(d * a[n]) * hh[n] + dx * u2f(ds[RNK + n]);

        if (PASS == 1) {
            S += d;
        } else {
            float y = xv * dpe;
            #pragma unroll
            for (int n = 0; n < DS; n++) y += hh[n] * u2f(ds2[n]);
            bf16 yb = f2b(y);
            xrow[(size_t)t * DI] = *(unsigned short*)&yb;
        }
    }
    if (PASS == 1) {
        #pragma unroll
        for (int n = 0; n < DS; n++) hst[sidx*DS + n] = hh[n];
        Ssum[sidx] = S;
    }
}

// ---------------- combine chunk states: hst becomes h_in per chunk ----------------
__global__ __launch_bounds__(256) void scan_combine_kernel(
    float* __restrict__ hst, const float* __restrict__ Ssum,
    const float* __restrict__ A_log)
{
    int tid = blockIdx.x * 256 + threadIdx.x;   // (b*DI+e)*16 + n
    int n = tid & 15;
    int bee = tid >> 4;
    int e = bee % DI;
    float a = -__expf(A_log[e*DS + n]);
    float run = 0.f;
    for (int c = 0; c < CHK; c++) {
        size_t idx = ((size_t)bee * CHK + c) * DS + n;
        float tmp = hst[idx];
        hst[idx] = run;                                   // h_in for chunk c
        run = tmp + __expf(a * Ssum[(size_t)bee*CHK + c]) * run;  // h_out of chunk c
    }
}

// ---------------- pooled[b,d] = (1/L) sum_t h[b,t,d]*rs[b,t]*wf[d] ----------------
__global__ __launch_bounds__(128) void pool_kernel(
    const bf16* __restrict__ h, const float* __restrict__ rs,
    const float* __restrict__ wf, float* __restrict__ pooled)
{
    int b = blockIdx.x, dc = blockIdx.y, tc = blockIdx.z;
    int d = dc * 128 + threadIdx.x;
    float s = 0.f;
    int t0 = tc * 128;
    for (int t = t0; t < t0 + 128; t++) {
        int row = b * LSEQ + t;
        s += b2f(h[(size_t)row * DM + d]) * rs[row];
    }
    atomicAdd(&pooled[b * DM + d], s * wf[d] * (1.f / LSEQ));
}

// ---------------- classifier head + log_softmax + NLL ----------------
__global__ __launch_bounds__(128) void head_kernel(
    const float* __restrict__ pooled, const float* __restrict__ cls_w,
    const float* __restrict__ cls_b, const int* __restrict__ labels,
    float* __restrict__ out)
{
    __shared__ float lg[80];
    int tid = threadIdx.x;
    if (tid < 80) {
        int b = tid / 10, c = tid % 10;
        float s = cls_b[c];
        for (int d = 0; d < DM; d++) s += pooled[b * DM + d] * cls_w[c * DM + d];
        lg[tid] = s;
    }
    __syncthreads();
    if (tid == 0) {
        float loss = 0.f;
        for (int b = 0; b < NBATCH; b++) {
            float mx = -1e30f;
            for (int c = 0; c < 10; c++) mx = fmaxf(mx, lg[b*10+c]);
            float se = 0.f;
            for (int c = 0; c < 10; c++) se += expf(lg[b*10+c] - mx);
            float lse = mx + logf(se);
            loss -= (lg[b*10 + labels[b]] - lse);
            for (int c = 0; c < 10; c++) out[b*10+c] = lg[b*10+c];
        }
        out[80] = loss / NBATCH;
    }
}

extern "C" void kernel_launch(void* const* d_in, const int* in_sizes, int n_in,
                              void* d_out, int out_size, void* d_ws, size_t ws_size,
                              hipStream_t stream) {
    const float* x          = (const float*)d_in[0];
    const int*   labels     = (const int*)d_in[1];
    const float* in_proj_w  = (const float*)d_in[2];
    const float* conv_w     = (const float*)d_in[3];
    const float* conv_b     = (const float*)d_in[4];
    const float* x_proj_w   = (const float*)d_in[5];
    const float* dt_w       = (const float*)d_in[6];
    const float* dt_b       = (const float*)d_in[7];
    const float* A_log      = (const float*)d_in[8];
    const float* D_param    = (const float*)d_in[9];
    const float* out_proj_w = (const float*)d_in[10];
    const float* norm_w     = (const float*)d_in[11];
    const float* normf_w    = (const float*)d_in[12];
    const float* cls_w      = (const float*)d_in[13];
    const float* cls_b      = (const float*)d_in[14];
    float* out = (float*)d_out;

    // workspace layout (~113 MB total)
    char* p = (char*)d_ws;
    bf16* h   = (bf16*)p;                 p += (size_t)MTOK * DM * 2;        // 25.2 MB
    bf16* xn  = (bf16*)p;                 p += (size_t)MTOK * DM * 2;        // 25.2 MB
    bf16* xy  = (bf16*)p;                 p += (size_t)MTOK * DI * 2;        // 50.3 MB (xin -> y)
    bf16* dbc = (bf16*)p;                 p += (size_t)MTOK * 80 * 2;        // 2.6 MB
    float* hst = (float*)p;               p += (size_t)NBATCH*DI*CHK*DS*4;   // 12.6 MB
    float* Ssum = (float*)p;              p += (size_t)NBATCH*DI*CHK*4;      // 0.8 MB
    unsigned short* bound = (unsigned short*)p; p += (size_t)NBATCH*DI*CHK*4*2; // 1.6 MB
    float* rsb    = (float*)p;            p += (size_t)MTOK * 4;
    float* pooled = (float*)p;            p += NBATCH * DM * 4;

    cvt_kernel<<<(MTOK * DM) / 256, 256, 0, stream>>>(x, h, MTOK * DM);
    hipMemsetAsync(pooled, 0, NBATCH * DM * sizeof(float), stream);

    int scan_grid = (DI/256) * NBATCH * CHK;   // 768

    for (int l = 0; l < 4; l++) {
        const float* inw = in_proj_w + (size_t)l * 2 * DI * DM;
        const float* cwl = conv_w + (size_t)l * DI * 4;
        const float* cbl = conv_b + (size_t)l * DI;
        const float* xwl = x_proj_w + (size_t)l * (RNK + 2*DS) * DI;
        const float* dwl = dt_w + (size_t)l * DI * RNK;
        const float* dbl = dt_b + (size_t)l * DI;
        const float* All = A_log + (size_t)l * DI * DS;
        const float* Dpl = D_param + (size_t)l * DI;
        const float* owl = out_proj_w + (size_t)l * DM * DI;

        rmsnorm_kernel<<<MTOK, 256, 0, stream>>>(h, norm_w + (size_t)l * DM, xn, nullptr);

        // xin = xn @ in_w[0:1536]^T
        gemm_kernel<0><<<dim3(DI/64, MTOK/64), 256, 0, stream>>>(
            xn, DM, inw, DM, xy, DI, MTOK, DI, DM, nullptr, nullptr, 0);

        // dbc = silu(conv(xin)) @ xw^T   (conv fused into A-loader)
        gemm_kernel<1><<<dim3(2, MTOK/64), 256, 0, stream>>>(
            xy, DI, xwl, DI, dbc, 80, MTOK, 80, DI, cwl, cbl, 0);

        // chunked scan: pass1 -> combine -> pass2 (y overwrites xin in xy)
        scan_pass_kernel<1><<<scan_grid, 256, 0, stream>>>(
            xy, dbc, All, Dpl, dwl, dbl, cwl, cbl, hst, Ssum, bound);
        scan_combine_kernel<<<(NBATCH*DI*DS)/256, 256, 0, stream>>>(hst, Ssum, All);
        scan_pass_kernel<2><<<scan_grid, 256, 0, stream>>>(
            xy, dbc, All, Dpl, dwl, dbl, cwl, cbl, hst, Ssum, bound);

        // gating: y *= silu(xn @ in_w[1536:3072]^T)
        gemm_kernel<0><<<dim3(DI/64, MTOK/64), 256, 0, stream>>>(
            xn, DM, inw + (size_t)DI * DM, DM, xy, DI, MTOK, DI, DM, nullptr, nullptr, 3);

        // h += y @ out_w^T
        gemm_kernel<0><<<dim3(DM/64, MTOK/64), 256, 0, stream>>>(
            xy, DI, owl, DI, h, DM, MTOK, DM, DI, nullptr, nullptr, 2);
    }

    rmsnorm_kernel<<<MTOK, 256, 0, stream>>>(h, normf_w, nullptr, rsb);
    pool_kernel<<<dim3(NBATCH, DM/128, LSEQ/128), 128, 0, stream>>>(h, rsb, normf_w, pooled);
    head_kernel<<<1, 128, 0, stream>>>(pooled, cls_w, cls_b, labels, out);
}

// Round 4
// 1540.586 us; speedup vs baseline: 11.4522x; 5.3018x over previous
//
#include <hip/hip_runtime.h>
#include <hip/hip_bf16.h>
#include <math.h>

#define MTOK 16384      // B*L tokens
#define DM   768
#define DI   1536
#define DS   16
#define RNK  48
#define LSEQ 2048
#define NBATCH 8
#define EPSV 1e-5f
#define CHK  16         // time chunks for the scan
#define CLEN (LSEQ / CHK)
#define BM 128
#define BN 128
#define BK 32

typedef __hip_bfloat16 bf16;
typedef __attribute__((ext_vector_type(8))) short short8;
typedef __attribute__((ext_vector_type(4))) float floatx4;

__device__ __forceinline__ float b2f(bf16 v){ return __bfloat162float(v); }
__device__ __forceinline__ bf16  f2b(float v){ return __float2bfloat16(v); }
__device__ __forceinline__ float u2f(unsigned short u){
    union { unsigned int i; float f; } v; v.i = ((unsigned int)u) << 16; return v.f;
}
__device__ __forceinline__ float silu_f(float x){
    return x * __builtin_amdgcn_rcpf(1.f + __expf(-x));
}
__device__ __forceinline__ void gload_lds16(const void* g, void* l) {
    __builtin_amdgcn_global_load_lds(
        (const __attribute__((address_space(1))) void*)g,
        (__attribute__((address_space(3))) void*)l, 16, 0, 0);
}

// ---------------- fp32 -> bf16 convert ----------------
__global__ __launch_bounds__(256) void cvt_kernel(
    const float* __restrict__ x, bf16* __restrict__ h, int n)
{
    int i = blockIdx.x * 256 + threadIdx.x;
    if (i < n) h[i] = f2b(x[i]);
}

// ---------------- RMSNorm over 768 (3 elems/thread) ----------------
__global__ __launch_bounds__(256) void rmsnorm_kernel(
    const bf16* __restrict__ in, const float* __restrict__ w,
    bf16* __restrict__ out, float* __restrict__ rs_out)
{
    int row = blockIdx.x;
    const bf16* r = in + (size_t)row * DM;
    float v0 = b2f(r[threadIdx.x]);
    float v1 = b2f(r[threadIdx.x + 256]);
    float v2 = b2f(r[threadIdx.x + 512]);
    float s = v0*v0 + v1*v1 + v2*v2;
    for (int o = 32; o > 0; o >>= 1) s += __shfl_down(s, o, 64);
    __shared__ float red[4];
    if ((threadIdx.x & 63) == 0) red[threadIdx.x >> 6] = s;
    __syncthreads();
    float rs = rsqrtf((red[0]+red[1]+red[2]+red[3]) * (1.f/DM) + EPSV);
    if (rs_out && threadIdx.x == 0) rs_out[row] = rs;
    if (out) {
        out[(size_t)row*DM + threadIdx.x]       = f2b(v0 * rs * w[threadIdx.x]);
        out[(size_t)row*DM + threadIdx.x + 256] = f2b(v1 * rs * w[threadIdx.x + 256]);
        out[(size_t)row*DM + threadIdx.x + 512] = f2b(v2 * rs * w[threadIdx.x + 512]);
    }
}

// ---------------- bf16 MFMA GEMM: C[M,N] (op)= A[M,K] @ W[N,K]^T ----------------
// 128x128 tile, BK=32, 4 waves 2x2, each wave 4x4 mfma_f32_16x16x32_bf16.
// MODE 0: C = acc ; MODE 2: C += acc ; MODE 3: C = C * silu(acc)
// CONVA=1: A-tile = silu(causal dwconv4(A)) computed on the fly (x_proj path)
template<int MODE, int CONVA>
__global__ __launch_bounds__(256) void mgemm(
    const short* __restrict__ A, int lda,
    const short* __restrict__ W, int ldw,
    bf16* __restrict__ C, int ldc,
    int M, int N, int K,
    const float* __restrict__ cw, const float* __restrict__ cb)
{
    __shared__ __attribute__((aligned(16))) short As[BM*BK];
    __shared__ __attribute__((aligned(16))) short Bs[BN*BK];
    const int bm = blockIdx.y * BM;
    const int bn = blockIdx.x * BN;
    const int tid = threadIdx.x;
    const int wave = tid >> 6;
    const int lane = tid & 63;
    const int wm = (wave & 1) * 64;
    const int wn = (wave >> 1) * 64;
    const int r15 = lane & 15;
    const int quad = lane >> 4;

    const int srow = wave*32 + (lane >> 2);
    const int scol = (lane & 3) * 8;
    int wr0 = bn + srow;      if (wr0 >= N) wr0 = N - 1;
    int wr1 = bn + srow + 16; if (wr1 >= N) wr1 = N - 1;

    floatx4 acc[4][4];
    const floatx4 zero = {0.f, 0.f, 0.f, 0.f};
    #pragma unroll
    for (int i = 0; i < 4; i++)
        #pragma unroll
        for (int j = 0; j < 4; j++) acc[i][j] = zero;

    const int kk = tid & 31;    // CONVA: column within A-tile
    const int tg = tid >> 5;    // CONVA: row group (16 rows)

    for (int k0 = 0; k0 < K; k0 += BK) {
        if (CONVA) {
            int e = k0 + kk;
            float c0 = cw[e*4+0], c1 = cw[e*4+1], c2 = cw[e*4+2], c3 = cw[e*4+3];
            float cbe = cb[e];
            int g0 = bm + tg*16;
            const unsigned short* xp = (const unsigned short*)A + (size_t)g0 * lda + e;
            float p0 = 0.f, p1 = 0.f, p2 = 0.f;
            if ((g0 & (LSEQ-1)) != 0) {
                p0 = u2f(xp[-(ptrdiff_t)3*lda]);
                p1 = u2f(xp[-(ptrdiff_t)2*lda]);
                p2 = u2f(xp[-(ptrdiff_t)1*lda]);
            }
            #pragma unroll
            for (int i = 0; i < 16; i++) {
                float xt = u2f(xp[(size_t)i * lda]);
                float xv = silu_f(cbe + c0*p0 + c1*p1 + c2*p2 + c3*xt);
                p0 = p1; p1 = p2; p2 = xt;
                bf16 t = f2b(xv);
                As[(tg*16 + i)*BK + kk] = *(short*)&t;
            }
        } else {
            gload_lds16(A + (size_t)(bm + srow)      * lda + k0 + scol, &As[(wave*32)*BK]);
            gload_lds16(A + (size_t)(bm + srow + 16) * lda + k0 + scol, &As[(wave*32 + 16)*BK]);
        }
        gload_lds16(W + (size_t)wr0 * ldw + k0 + scol, &Bs[(wave*32)*BK]);
        gload_lds16(W + (size_t)wr1 * ldw + k0 + scol, &Bs[(wave*32 + 16)*BK]);
        __syncthreads();

        short8 af[4], bfr[4];
        #pragma unroll
        for (int i = 0; i < 4; i++) af[i]  = *(const short8*)&As[(wm + i*16 + r15)*BK + quad*8];
        #pragma unroll
        for (int i = 0; i < 4; i++) bfr[i] = *(const short8*)&Bs[(wn + i*16 + r15)*BK + quad*8];
        #pragma unroll
        for (int mt = 0; mt < 4; mt++)
            #pragma unroll
            for (int nt = 0; nt < 4; nt++)
                acc[mt][nt] = __builtin_amdgcn_mfma_f32_16x16x32_bf16(
                    af[mt], bfr[nt], acc[mt][nt], 0, 0, 0);
        __syncthreads();
    }

    // epilogue: D row(m) = quad*4 + reg, col(n) = r15 (verified C/D mapping)
    #pragma unroll
    for (int nt = 0; nt < 4; nt++) {
        int n = bn + wn + nt*16 + r15;
        if (n >= N) continue;
        #pragma unroll
        for (int mt = 0; mt < 4; mt++) {
            #pragma unroll
            for (int reg = 0; reg < 4; reg++) {
                int m = bm + wm + mt*16 + quad*4 + reg;
                size_t off = (size_t)m * ldc + n;
                float v = acc[mt][nt][reg];
                if (MODE == 2)      C[off] = f2b(b2f(C[off]) + v);
                else if (MODE == 3) C[off] = f2b(b2f(C[off]) * silu_f(v));
                else                C[off] = f2b(v);
            }
        }
    }
}

// ---------------- chunked selective scan, no shuffles ----------------
template<int PASS>
__global__ __launch_bounds__(256) void scan_pass_kernel(
    bf16* __restrict__ xy,              // [M,1536]  xin (PASS2: y overwrites)
    const bf16* __restrict__ dbc,       // [M,80]  dt_r | B | C
    const float* __restrict__ A_log,    // [1536,16] layer slice
    const float* __restrict__ Dp,       // [1536]
    const float* __restrict__ dtw,      // [1536,48]
    const float* __restrict__ dtb,      // [1536]
    const float* __restrict__ cw,       // [1536,4]
    const float* __restrict__ cb,       // [1536]
    float* __restrict__ hst,            // [B*DI, CHK, 16]
    float* __restrict__ Ssum,           // [B*DI, CHK]
    unsigned short* __restrict__ bound) // [B*DI, CHK, 4]
{
    int e = (blockIdx.x % (DI/256)) * 256 + threadIdx.x;
    int b = (blockIdx.x / (DI/256)) & (NBATCH - 1);
    int c = blockIdx.x / ((DI/256) * NBATCH);
    int t0 = c * CLEN;

    float w[RNK];
    #pragma unroll
    for (int r = 0; r < RNK; r++) w[r] = dtw[e*RNK + r];
    float a[DS];
    #pragma unroll
    for (int n = 0; n < DS; n++) a[n] = -__expf(A_log[e*DS + n]);
    float c0 = cw[e*4+0], c1 = cw[e*4+1], c2 = cw[e*4+2], c3 = cw[e*4+3];
    float cbe = cb[e], dtbe = dtb[e], dpe = Dp[e];

    size_t sidx = ((size_t)(b*DI) + e) * CHK + c;
    float hh[DS];
    if (PASS == 1) {
        #pragma unroll
        for (int n = 0; n < DS; n++) hh[n] = 0.f;
    } else {
        #pragma unroll
        for (int n = 0; n < DS; n++) hh[n] = hst[sidx*DS + n];
    }

    unsigned short* xrow = (unsigned short*)(xy + ((size_t)(b*LSEQ) + t0) * DI + e);
    const unsigned short* drow = (const unsigned short*)(dbc + ((size_t)(b*LSEQ) + t0) * 80);

    unsigned short r0, r1, r2;
    if (PASS == 1) {
        if (c == 0) { r0 = 0; r1 = 0; r2 = 0; }
        else {
            r0 = xrow[-(ptrdiff_t)3*DI];
            r1 = xrow[-(ptrdiff_t)2*DI];
            r2 = xrow[-(ptrdiff_t)1*DI];
        }
        bound[sidx*4+0] = r0; bound[sidx*4+1] = r1; bound[sidx*4+2] = r2;
    } else {
        r0 = bound[sidx*4+0]; r1 = bound[sidx*4+1]; r2 = bound[sidx*4+2];
    }
    float p0 = u2f(r0), p1 = u2f(r1), p2 = u2f(r2);

    float S = 0.f;
    for (int t = 0; t < CLEN; t++) {
        float xt = u2f(xrow[(size_t)t * DI]);
        float xv = silu_f(cbe + c0*p0 + c1*p1 + c2*p2 + c3*xt);
        p0 = p1; p1 = p2; p2 = xt;

        uint4 q[5];
        const uint4* d4 = (const uint4*)(drow + (size_t)t * 80);
        #pragma unroll
        for (int i = 0; i < 5; i++) q[i] = d4[i];
        uint4 q2[5];
        #pragma unroll
        for (int i = 0; i < 5; i++) q2[i] = d4[5 + i];
        const unsigned short* ds = (const unsigned short*)q;
        const unsigned short* ds2 = (const unsigned short*)q2;

        float acc = dtbe;
        #pragma unroll
        for (int r = 0; r < RNK; r++) acc += w[r] * u2f(ds[r]);
        float d = (acc > 20.f) ? acc : __logf(1.f + __expf(acc));
        float dx = d * xv;
        #pragma unroll
        for (int n = 0; n < DS; n++)
            hh[n] = __expf(d * a[n]) * hh[n] + dx * u2f(ds[RNK + n]);

        if (PASS == 1) {
            S += d;
        } else {
            float y = xv * dpe;
            #pragma unroll
            for (int n = 0; n < DS; n++) y += hh[n] * u2f(ds2[n]);
            bf16 yb = f2b(y);
            xrow[(size_t)t * DI] = *(unsigned short*)&yb;
        }
    }
    if (PASS == 1) {
        #pragma unroll
        for (int n = 0; n < DS; n++) hst[sidx*DS + n] = hh[n];
        Ssum[sidx] = S;
    }
}

// ---------------- combine chunk states ----------------
__global__ __launch_bounds__(256) void scan_combine_kernel(
    float* __restrict__ hst, const float* __restrict__ Ssum,
    const float* __restrict__ A_log)
{
    int tid = blockIdx.x * 256 + threadIdx.x;
    int n = tid & 15;
    int bee = tid >> 4;
    int e = bee % DI;
    float a = -__expf(A_log[e*DS + n]);
    float run = 0.f;
    for (int c = 0; c < CHK; c++) {
        size_t idx = ((size_t)bee * CHK + c) * DS + n;
        float tmp = hst[idx];
        hst[idx] = run;
        run = tmp + __expf(a * Ssum[(size_t)bee*CHK + c]) * run;
    }
}

// ---------------- pooled[b,d] = (1/L) sum_t h[b,t,d]*rs[b,t]*wf[d] ----------------
__global__ __launch_bounds__(128) void pool_kernel(
    const bf16* __restrict__ h, const float* __restrict__ rs,
    const float* __restrict__ wf, float* __restrict__ pooled)
{
    int b = blockIdx.x, dc = blockIdx.y, tc = blockIdx.z;
    int d = dc * 128 + threadIdx.x;
    float s = 0.f;
    int t0 = tc * 128;
    for (int t = t0; t < t0 + 128; t++) {
        int row = b * LSEQ + t;
        s += b2f(h[(size_t)row * DM + d]) * rs[row];
    }
    atomicAdd(&pooled[b * DM + d], s * wf[d] * (1.f / LSEQ));
}

// ---------------- classifier head + log_softmax + NLL ----------------
__global__ __launch_bounds__(128) void head_kernel(
    const float* __restrict__ pooled, const float* __restrict__ cls_w,
    const float* __restrict__ cls_b, const int* __restrict__ labels,
    float* __restrict__ out)
{
    __shared__ float lg[80];
    int tid = threadIdx.x;
    if (tid < 80) {
        int b = tid / 10, c = tid % 10;
        float s = cls_b[c];
        for (int d = 0; d < DM; d++) s += pooled[b * DM + d] * cls_w[c * DM + d];
        lg[tid] = s;
    }
    __syncthreads();
    if (tid == 0) {
        float loss = 0.f;
        for (int b = 0; b < NBATCH; b++) {
            float mx = -1e30f;
            for (int c = 0; c < 10; c++) mx = fmaxf(mx, lg[b*10+c]);
            float se = 0.f;
            for (int c = 0; c < 10; c++) se += expf(lg[b*10+c] - mx);
            float lse = mx + logf(se);
            loss -= (lg[b*10 + labels[b]] - lse);
            for (int c = 0; c < 10; c++) out[b*10+c] = lg[b*10+c];
        }
        out[80] = loss / NBATCH;
    }
}

extern "C" void kernel_launch(void* const* d_in, const int* in_sizes, int n_in,
                              void* d_out, int out_size, void* d_ws, size_t ws_size,
                              hipStream_t stream) {
    const float* x          = (const float*)d_in[0];
    const int*   labels     = (const int*)d_in[1];
    const float* in_proj_w  = (const float*)d_in[2];
    const float* conv_w     = (const float*)d_in[3];
    const float* conv_b     = (const float*)d_in[4];
    const float* x_proj_w   = (const float*)d_in[5];
    const float* dt_w       = (const float*)d_in[6];
    const float* dt_b       = (const float*)d_in[7];
    const float* A_log      = (const float*)d_in[8];
    const float* D_param    = (const float*)d_in[9];
    const float* out_proj_w = (const float*)d_in[10];
    const float* norm_w     = (const float*)d_in[11];
    const float* normf_w    = (const float*)d_in[12];
    const float* cls_w      = (const float*)d_in[13];
    const float* cls_b      = (const float*)d_in[14];
    float* out = (float*)d_out;

    // workspace layout (~121 MB total)
    char* p = (char*)d_ws;
    bf16* h   = (bf16*)p;                 p += (size_t)MTOK * DM * 2;        // 25.2 MB
    bf16* xn  = (bf16*)p;                 p += (size_t)MTOK * DM * 2;        // 25.2 MB
    bf16* xy  = (bf16*)p;                 p += (size_t)MTOK * DI * 2;        // 50.3 MB (xin -> y)
    bf16* dbc = (bf16*)p;                 p += (size_t)MTOK * 80 * 2;        // 2.6 MB
    float* hst = (float*)p;               p += (size_t)NBATCH*DI*CHK*DS*4;   // 12.6 MB
    float* Ssum = (float*)p;              p += (size_t)NBATCH*DI*CHK*4;      // 0.8 MB
    unsigned short* bound = (unsigned short*)p; p += (size_t)NBATCH*DI*CHK*4*2; // 1.6 MB
    float* rsb    = (float*)p;            p += (size_t)MTOK * 4;
    float* pooled = (float*)p;            p += NBATCH * DM * 4;
    short* inw_b = (short*)p;             p += (size_t)2*DI*DM * 2;          // 4.7 MB (per-layer)
    short* xw_b  = (short*)p;             p += (size_t)80*DI * 2;            // 0.25 MB
    short* ow_b  = (short*)p;             p += (size_t)DM*DI * 2;            // 2.4 MB

    cvt_kernel<<<(MTOK * DM) / 256, 256, 0, stream>>>(x, h, MTOK * DM);
    hipMemsetAsync(pooled, 0, NBATCH * DM * sizeof(float), stream);

    int scan_grid = (DI/256) * NBATCH * CHK;   // 768

    for (int l = 0; l < 4; l++) {
        const float* inw = in_proj_w + (size_t)l * 2 * DI * DM;
        const float* cwl = conv_w + (size_t)l * DI * 4;
        const float* cbl = conv_b + (size_t)l * DI;
        const float* xwl = x_proj_w + (size_t)l * (RNK + 2*DS) * DI;
        const float* dwl = dt_w + (size_t)l * DI * RNK;
        const float* dbl = dt_b + (size_t)l * DI;
        const float* All = A_log + (size_t)l * DI * DS;
        const float* Dpl = D_param + (size_t)l * DI;
        const float* owl = out_proj_w + (size_t)l * DM * DI;

        // per-layer weight conversion fp32 -> bf16 (reused buffers)
        cvt_kernel<<<(2*DI*DM)/256, 256, 0, stream>>>(inw, (bf16*)inw_b, 2*DI*DM);
        cvt_kernel<<<(80*DI)/256, 256, 0, stream>>>(xwl, (bf16*)xw_b, 80*DI);
        cvt_kernel<<<(DM*DI)/256, 256, 0, stream>>>(owl, (bf16*)ow_b, DM*DI);

        rmsnorm_kernel<<<MTOK, 256, 0, stream>>>(h, norm_w + (size_t)l * DM, xn, nullptr);

        // xin = xn @ in_w[0:1536]^T   (MFMA)
        mgemm<0,0><<<dim3(DI/BN, MTOK/BM), 256, 0, stream>>>(
            (const short*)xn, DM, inw_b, DM, xy, DI, MTOK, DI, DM, nullptr, nullptr);

        // dbc = silu(conv(xin)) @ xw^T   (MFMA, conv fused into A staging)
        mgemm<0,1><<<dim3(1, MTOK/BM), 256, 0, stream>>>(
            (const short*)xy, DI, xw_b, DI, dbc, 80, MTOK, 80, DI, cwl, cbl);

        // chunked scan: pass1 -> combine -> pass2 (y overwrites xin in xy)
        scan_pass_kernel<1><<<scan_grid, 256, 0, stream>>>(
            xy, dbc, All, Dpl, dwl, dbl, cwl, cbl, hst, Ssum, bound);
        scan_combine_kernel<<<(NBATCH*DI*DS)/256, 256, 0, stream>>>(hst, Ssum, All);
        scan_pass_kernel<2><<<scan_grid, 256, 0, stream>>>(
            xy, dbc, All, Dpl, dwl, dbl, cwl, cbl, hst, Ssum, bound);

        // gating: y *= silu(xn @ in_w[1536:3072]^T)   (MFMA)
        mgemm<3,0><<<dim3(DI/BN, MTOK/BM), 256, 0, stream>>>(
            (const short*)xn, DM, inw_b + (size_t)DI*DM, DM, xy, DI, MTOK, DI, DM, nullptr, nullptr);

        // h += y @ out_w^T   (MFMA)
        mgemm<2,0><<<dim3(DM/BN, MTOK/BM), 256, 0, stream>>>(
            (const short*)xy, DI, ow_b, DI, h, DM, MTOK, DM, DI, nullptr, nullptr);
    }

    rmsnorm_kernel<<<MTOK, 256, 0, stream>>>(h, normf_w, nullptr, rsb);
    pool_kernel<<<dim3(NBATCH, DM/128, LSEQ/128), 128, 0, stream>>>(h, rsb, normf_w, pooled);
    head_kernel<<<1, 128, 0, stream>>>(pooled, cls_w, cls_b, labels, out);
}

// Round 6
// 1427.195 us; speedup vs baseline: 12.3621x; 1.0795x over previous
//
#include <hip/hip_runtime.h>
#include <hip/hip_bf16.h>
#include <math.h>

#define MTOK 16384      // B*L tokens
#define DM   768
#define DI   1536
#define DS   16
#define RNK  48
#define LSEQ 2048
#define NBATCH 8
#define EPSV 1e-5f
#define CHK  16         // time chunks for the scan
#define CLEN (LSEQ / CHK)
#define BM 128
#define BN 128
#define BK 32
#define EPS_STRIDE 72   // epilogue LDS row stride (shorts), 16B-aligned, conflict-light

typedef __hip_bfloat16 bf16;
typedef __attribute__((ext_vector_type(8))) short short8;
typedef __attribute__((ext_vector_type(4))) float floatx4;

__device__ __forceinline__ float b2f(bf16 v){ return __bfloat162float(v); }
__device__ __forceinline__ bf16  f2b(float v){ return __float2bfloat16(v); }
__device__ __forceinline__ float u2f(unsigned short u){
    union { unsigned int i; float f; } v; v.i = ((unsigned int)u) << 16; return v.f;
}
__device__ __forceinline__ float silu_f(float x){
    return x * __builtin_amdgcn_rcpf(1.f + __expf(-x));
}
__device__ __forceinline__ void gload_lds16(const void* g, void* l) {
    __builtin_amdgcn_global_load_lds(
        (const __attribute__((address_space(1))) void*)g,
        (__attribute__((address_space(3))) void*)l, 16, 0, 0);
}

// ---------------- fp32 -> bf16 convert ----------------
__global__ __launch_bounds__(256) void cvt_kernel(
    const float* __restrict__ x, bf16* __restrict__ h, int n)
{
    int i = blockIdx.x * 256 + threadIdx.x;
    if (i < n) h[i] = f2b(x[i]);
}

// ---------------- RMSNorm over 768 (3 elems/thread) ----------------
__global__ __launch_bounds__(256) void rmsnorm_kernel(
    const bf16* __restrict__ in, const float* __restrict__ w,
    bf16* __restrict__ out, float* __restrict__ rs_out)
{
    int row = blockIdx.x;
    const bf16* r = in + (size_t)row * DM;
    float v0 = b2f(r[threadIdx.x]);
    float v1 = b2f(r[threadIdx.x + 256]);
    float v2 = b2f(r[threadIdx.x + 512]);
    float s = v0*v0 + v1*v1 + v2*v2;
    for (int o = 32; o > 0; o >>= 1) s += __shfl_down(s, o, 64);
    __shared__ float red[4];
    if ((threadIdx.x & 63) == 0) red[threadIdx.x >> 6] = s;
    __syncthreads();
    float rs = rsqrtf((red[0]+red[1]+red[2]+red[3]) * (1.f/DM) + EPSV);
    if (rs_out && threadIdx.x == 0) rs_out[row] = rs;
    if (out) {
        out[(size_t)row*DM + threadIdx.x]       = f2b(v0 * rs * w[threadIdx.x]);
        out[(size_t)row*DM + threadIdx.x + 256] = f2b(v1 * rs * w[threadIdx.x + 256]);
        out[(size_t)row*DM + threadIdx.x + 512] = f2b(v2 * rs * w[threadIdx.x + 512]);
    }
}

// ---------------- bf16 MFMA GEMM: C[M,N] (op)= A[M,K] @ W[N,K]^T ----------------
// 128x128 tile, BK=32, 4 waves 2x2, each wave 4x4 mfma_f32_16x16x32_bf16.
// XOR-swizzled LDS tiles (8-way -> 4-way bank conflicts), wide-store epilogue
// via per-wave LDS bounce.
// MODE 0: C = acc ; MODE 2: C += acc ; MODE 3: C = C * silu(acc)
// CONVA=1: A-tile = silu(causal dwconv4(A)) computed on the fly (x_proj path)
template<int MODE, int CONVA>
__global__ __launch_bounds__(256) void mgemm(
    const short* __restrict__ A, int lda,
    const short* __restrict__ W, int ldw,
    bf16* __restrict__ C, int ldc,
    int M, int N, int K,
    const float* __restrict__ cw, const float* __restrict__ cb)
{
    __shared__ __attribute__((aligned(16))) short As[BM*BK];
    __shared__ __attribute__((aligned(16))) short Bs[BN*BK];
    const int bm = blockIdx.y * BM;
    const int bn = blockIdx.x * BN;
    const int tid = threadIdx.x;
    const int wave = tid >> 6;
    const int lane = tid & 63;
    const int wm = (wave & 1) * 64;
    const int wn = (wave >> 1) * 64;
    const int r15 = lane & 15;
    const int quad = lane >> 4;

    const int srow = wave*32 + (lane >> 2);
    // XOR-swizzled staging column-chunk (chunk ^ localrow&3); row&3 == (lane>>2)&3
    const int swz = (lane & 3) ^ ((lane >> 2) & 3);
    int wr0 = bn + srow;      if (wr0 >= N) wr0 = N - 1;
    int wr1 = bn + srow + 16; if (wr1 >= N) wr1 = N - 1;

    floatx4 acc[4][4];
    const floatx4 zero = {0.f, 0.f, 0.f, 0.f};
    #pragma unroll
    for (int i = 0; i < 4; i++)
        #pragma unroll
        for (int j = 0; j < 4; j++) acc[i][j] = zero;

    const int kk = tid & 31;    // CONVA: column within A-tile
    const int tg = tid >> 5;    // CONVA: row group (16 rows)
    // fragment-read swizzle: A unswizzled when CONVA (ds_write staging)
    const int sA = CONVA ? quad : (quad ^ (r15 & 3));
    const int sB = quad ^ (r15 & 3);

    for (int k0 = 0; k0 < K; k0 += BK) {
        if (CONVA) {
            int e = k0 + kk;
            float c0 = cw[e*4+0], c1 = cw[e*4+1], c2 = cw[e*4+2], c3 = cw[e*4+3];
            float cbe = cb[e];
            int g0 = bm + tg*16;
            const unsigned short* xp = (const unsigned short*)A + (size_t)g0 * lda + e;
            float p0 = 0.f, p1 = 0.f, p2 = 0.f;
            if ((g0 & (LSEQ-1)) != 0) {
                p0 = u2f(xp[-(ptrdiff_t)3*lda]);
                p1 = u2f(xp[-(ptrdiff_t)2*lda]);
                p2 = u2f(xp[-(ptrdiff_t)1*lda]);
            }
            #pragma unroll
            for (int i = 0; i < 16; i++) {
                float xt = u2f(xp[(size_t)i * lda]);
                float xv = silu_f(cbe + c0*p0 + c1*p1 + c2*p2 + c3*xt);
                p0 = p1; p1 = p2; p2 = xt;
                bf16 t = f2b(xv);
                As[(tg*16 + i)*BK + kk] = *(short*)&t;
            }
        } else {
            gload_lds16(A + (size_t)(bm + srow)      * lda + k0 + swz*8, &As[(wave*32)*BK]);
            gload_lds16(A + (size_t)(bm + srow + 16) * lda + k0 + swz*8, &As[(wave*32 + 16)*BK]);
        }
        gload_lds16(W + (size_t)wr0 * ldw + k0 + swz*8, &Bs[(wave*32)*BK]);
        gload_lds16(W + (size_t)wr1 * ldw + k0 + swz*8, &Bs[(wave*32 + 16)*BK]);
        __syncthreads();

        short8 af[4], bfr[4];
        #pragma unroll
        for (int i = 0; i < 4; i++) af[i]  = *(const short8*)&As[(wm + i*16 + r15)*BK + sA*8];
        #pragma unroll
        for (int i = 0; i < 4; i++) bfr[i] = *(const short8*)&Bs[(wn + i*16 + r15)*BK + sB*8];
        #pragma unroll
        for (int mt = 0; mt < 4; mt++)
            #pragma unroll
            for (int nt = 0; nt < 4; nt++)
                acc[mt][nt] = __builtin_amdgcn_mfma_f32_16x16x32_bf16(
                    af[mt], bfr[nt], acc[mt][nt], 0, 0, 0);
        __syncthreads();
    }

    // ---- wide-store epilogue: bounce each wave's 64x64 tile through LDS ----
    // per-wave private region (1152 shorts, stride 72); K-loop's trailing
    // barrier guarantees As/Bs are free for reuse.
    short* ep = ((wave & 2) ? Bs : As) + (wave & 1) * 1152;
    const int lr = lane >> 2;
    const int lc = lane & 3;
    #pragma unroll
    for (int mt = 0; mt < 4; mt++) {
        #pragma unroll
        for (int nt = 0; nt < 4; nt++)
            #pragma unroll
            for (int reg = 0; reg < 4; reg++) {
                bf16 t = f2b(acc[mt][nt][reg]);
                ep[(quad*4 + reg)*EPS_STRIDE + nt*16 + r15] = *(short*)&t;
            }
        // read back row-major: lane -> row lr, 16-col chunk lc (32 B)
        short8 v0 = *(const short8*)&ep[lr*EPS_STRIDE + lc*16];
        short8 v1 = *(const short8*)&ep[lr*EPS_STRIDE + lc*16 + 8];
        int gm = bm + wm + mt*16 + lr;
        int gn = bn + wn + lc*16;
        if (gn < N) {
            bf16* cp = C + (size_t)gm * ldc + gn;
            if (MODE == 0) {
                *(short8*)cp       = v0;
                *(short8*)(cp + 8) = v1;
            } else {
                short8 c0 = *(const short8*)cp;
                short8 c1 = *(const short8*)(cp + 8);
                short8 o0, o1;
                #pragma unroll
                for (int j = 0; j < 8; j++) {
                    float cv0 = u2f((unsigned short)c0[j]);
                    float av0 = u2f((unsigned short)v0[j]);
                    float cv1 = u2f((unsigned short)c1[j]);
                    float av1 = u2f((unsigned short)v1[j]);
                    float r0 = (MODE == 2) ? (cv0 + av0) : (cv0 * silu_f(av0));
                    float r1 = (MODE == 2) ? (cv1 + av1) : (cv1 * silu_f(av1));
                    bf16 t0 = f2b(r0), t1 = f2b(r1);
                    o0[j] = *(short*)&t0;
                    o1[j] = *(short*)&t1;
                }
                *(short8*)cp       = o0;
                *(short8*)(cp + 8) = o1;
            }
        }
    }
}

// ---------------- chunked selective scan, no shuffles ----------------
template<int PASS>
__global__ __launch_bounds__(256) void scan_pass_kernel(
    bf16* __restrict__ xy,              // [M,1536]  xin (PASS2: y overwrites)
    const bf16* __restrict__ dbc,       // [M,80]  dt_r | B | C
    const float* __restrict__ A_log,    // [1536,16] layer slice
    const float* __restrict__ Dp,       // [1536]
    const float* __restrict__ dtw,      // [1536,48]
    const float* __restrict__ dtb,      // [1536]
    const float* __restrict__ cw,       // [1536,4]
    const float* __restrict__ cb,       // [1536]
    float* __restrict__ hst,            // [B*DI, CHK, 16]
    float* __restrict__ Ssum,           // [B*DI, CHK]
    unsigned short* __restrict__ bound) // [B*DI, CHK, 4]
{
    int e = (blockIdx.x % (DI/256)) * 256 + threadIdx.x;
    int b = (blockIdx.x / (DI/256)) & (NBATCH - 1);
    int c = blockIdx.x / ((DI/256) * NBATCH);
    int t0 = c * CLEN;

    float w[RNK];
    #pragma unroll
    for (int r = 0; r < RNK; r++) w[r] = dtw[e*RNK + r];
    float a[DS];
    #pragma unroll
    for (int n = 0; n < DS; n++) a[n] = -__expf(A_log[e*DS + n]);
    float c0 = cw[e*4+0], c1 = cw[e*4+1], c2 = cw[e*4+2], c3 = cw[e*4+3];
    float cbe = cb[e], dtbe = dtb[e], dpe = Dp[e];

    size_t sidx = ((size_t)(b*DI) + e) * CHK + c;
    float hh[DS];
    if (PASS == 1) {
        #pragma unroll
        for (int n = 0; n < DS; n++) hh[n] = 0.f;
    } else {
        #pragma unroll
        for (int n = 0; n < DS; n++) hh[n] = hst[sidx*DS + n];
    }

    unsigned short* xrow = (unsigned short*)(xy + ((size_t)(b*LSEQ) + t0) * DI + e);
    const unsigned short* drow = (const unsigned short*)(dbc + ((size_t)(b*LSEQ) + t0) * 80);

    unsigned short r0, r1, r2;
    if (PASS == 1) {
        if (c == 0) { r0 = 0; r1 = 0; r2 = 0; }
        else {
            r0 = xrow[-(ptrdiff_t)3*DI];
            r1 = xrow[-(ptrdiff_t)2*DI];
            r2 = xrow[-(ptrdiff_t)1*DI];
        }
        bound[sidx*4+0] = r0; bound[sidx*4+1] = r1; bound[sidx*4+2] = r2;
    } else {
        r0 = bound[sidx*4+0]; r1 = bound[sidx*4+1]; r2 = bound[sidx*4+2];
    }
    float p0 = u2f(r0), p1 = u2f(r1), p2 = u2f(r2);

    float S = 0.f;
    for (int t = 0; t < CLEN; t++) {
        float xt = u2f(xrow[(size_t)t * DI]);
        float xv = silu_f(cbe + c0*p0 + c1*p1 + c2*p2 + c3*xt);
        p0 = p1; p1 = p2; p2 = xt;

        uint4 q[5];
        const uint4* d4 = (const uint4*)(drow + (size_t)t * 80);
        #pragma unroll
        for (int i = 0; i < 5; i++) q[i] = d4[i];
        uint4 q2[5];
        #pragma unroll
        for (int i = 0; i < 5; i++) q2[i] = d4[5 + i];
        const unsigned short* ds = (const unsigned short*)q;
        const unsigned short* ds2 = (const unsigned short*)q2;

        float acc = dtbe;
        #pragma unroll
        for (int r = 0; r < RNK; r++) acc += w[r] * u2f(ds[r]);
        float d = (acc > 20.f) ? acc : __logf(1.f + __expf(acc));
        float dx = d * xv;
        #pragma unroll
        for (int n = 0; n < DS; n++)
            hh[n] = __expf(d * a[n]) * hh[n] + dx * u2f(ds[RNK + n]);

        if (PASS == 1) {
            S += d;
        } else {
            float y = xv * dpe;
            #pragma unroll
            for (int n = 0; n < DS; n++) y += hh[n] * u2f(ds2[n]);
            bf16 yb = f2b(y);
            xrow[(size_t)t * DI] = *(unsigned short*)&yb;
        }
    }
    if (PASS == 1) {
        #pragma unroll
        for (int n = 0; n < DS; n++) hst[sidx*DS + n] = hh[n];
        Ssum[sidx] = S;
    }
}

// ---------------- combine chunk states ----------------
__global__ __launch_bounds__(256) void scan_combine_kernel(
    float* __restrict__ hst, const float* __restrict__ Ssum,
    const float* __restrict__ A_log)
{
    int tid = blockIdx.x * 256 + threadIdx.x;
    int n = tid & 15;
    int bee = tid >> 4;
    int e = bee % DI;
    float a = -__expf(A_log[e*DS + n]);
    float run = 0.f;
    for (int c = 0; c < CHK; c++) {
        size_t idx = ((size_t)bee * CHK + c) * DS + n;
        float tmp = hst[idx];
        hst[idx] = run;
        run = tmp + __expf(a * Ssum[(size_t)bee*CHK + c]) * run;
    }
}

// ---------------- pooled[b,d] = (1/L) sum_t h[b,t,d]*rs[b,t]*wf[d] ----------------
__global__ __launch_bounds__(128) void pool_kernel(
    const bf16* __restrict__ h, const float* __restrict__ rs,
    const float* __restrict__ wf, float* __restrict__ pooled)
{
    int b = blockIdx.x, dc = blockIdx.y, tc = blockIdx.z;
    int d = dc * 128 + threadIdx.x;
    float s = 0.f;
    int t0 = tc * 128;
    for (int t = t0; t < t0 + 128; t++) {
        int row = b * LSEQ + t;
        s += b2f(h[(size_t)row * DM + d]) * rs[row];
    }
    atomicAdd(&pooled[b * DM + d], s * wf[d] * (1.f / LSEQ));
}

// ---------------- classifier head + log_softmax + NLL ----------------
__global__ __launch_bounds__(128) void head_kernel(
    const float* __restrict__ pooled, const float* __restrict__ cls_w,
    const float* __restrict__ cls_b, const int* __restrict__ labels,
    float* __restrict__ out)
{
    __shared__ float lg[80];
    int tid = threadIdx.x;
    if (tid < 80) {
        int b = tid / 10, c = tid % 10;
        float s = cls_b[c];
        for (int d = 0; d < DM; d++) s += pooled[b * DM + d] * cls_w[c * DM + d];
        lg[tid] = s;
    }
    __syncthreads();
    if (tid == 0) {
        float loss = 0.f;
        for (int b = 0; b < NBATCH; b++) {
            float mx = -1e30f;
            for (int c = 0; c < 10; c++) mx = fmaxf(mx, lg[b*10+c]);
            float se = 0.f;
            for (int c = 0; c < 10; c++) se += expf(lg[b*10+c] - mx);
            float lse = mx + logf(se);
            loss -= (lg[b*10 + labels[b]] - lse);
            for (int c = 0; c < 10; c++) out[b*10+c] = lg[b*10+c];
        }
        out[80] = loss / NBATCH;
    }
}

extern "C" void kernel_launch(void* const* d_in, const int* in_sizes, int n_in,
                              void* d_out, int out_size, void* d_ws, size_t ws_size,
                              hipStream_t stream) {
    const float* x          = (const float*)d_in[0];
    const int*   labels     = (const int*)d_in[1];
    const float* in_proj_w  = (const float*)d_in[2];
    const float* conv_w     = (const float*)d_in[3];
    const float* conv_b     = (const float*)d_in[4];
    const float* x_proj_w   = (const float*)d_in[5];
    const float* dt_w       = (const float*)d_in[6];
    const float* dt_b       = (const float*)d_in[7];
    const float* A_log      = (const float*)d_in[8];
    const float* D_param    = (const float*)d_in[9];
    const float* out_proj_w = (const float*)d_in[10];
    const float* norm_w     = (const float*)d_in[11];
    const float* normf_w    = (const float*)d_in[12];
    const float* cls_w      = (const float*)d_in[13];
    const float* cls_b      = (const float*)d_in[14];
    float* out = (float*)d_out;

    // workspace layout (~121 MB total, proven in R4)
    char* p = (char*)d_ws;
    bf16* h   = (bf16*)p;                 p += (size_t)MTOK * DM * 2;        // 25.2 MB
    bf16* xn  = (bf16*)p;                 p += (size_t)MTOK * DM * 2;        // 25.2 MB
    bf16* xy  = (bf16*)p;                 p += (size_t)MTOK * DI * 2;        // 50.3 MB (xin -> y)
    bf16* dbc = (bf16*)p;                 p += (size_t)MTOK * 80 * 2;        // 2.6 MB
    float* hst = (float*)p;               p += (size_t)NBATCH*DI*CHK*DS*4;   // 12.6 MB
    float* Ssum = (float*)p;              p += (size_t)NBATCH*DI*CHK*4;      // 0.8 MB
    unsigned short* bound = (unsigned short*)p; p += (size_t)NBATCH*DI*CHK*4*2; // 1.6 MB
    float* rsb    = (float*)p;            p += (size_t)MTOK * 4;
    float* pooled = (float*)p;            p += NBATCH * DM * 4;
    short* inw_b = (short*)p;             p += (size_t)2*DI*DM * 2;          // 4.7 MB (per-layer)
    short* xw_b  = (short*)p;             p += (size_t)80*DI * 2;            // 0.25 MB
    short* ow_b  = (short*)p;             p += (size_t)DM*DI * 2;            // 2.4 MB

    cvt_kernel<<<(MTOK * DM) / 256, 256, 0, stream>>>(x, h, MTOK * DM);
    hipMemsetAsync(pooled, 0, NBATCH * DM * sizeof(float), stream);

    int scan_grid = (DI/256) * NBATCH * CHK;   // 768

    for (int l = 0; l < 4; l++) {
        const float* inw = in_proj_w + (size_t)l * 2 * DI * DM;
        const float* cwl = conv_w + (size_t)l * DI * 4;
        const float* cbl = conv_b + (size_t)l * DI;
        const float* xwl = x_proj_w + (size_t)l * (RNK + 2*DS) * DI;
        const float* dwl = dt_w + (size_t)l * DI * RNK;
        const float* dbl = dt_b + (size_t)l * DI;
        const float* All = A_log + (size_t)l * DI * DS;
        const float* Dpl = D_param + (size_t)l * DI;
        const float* owl = out_proj_w + (size_t)l * DM * DI;

        // per-layer weight conversion fp32 -> bf16 (reused buffers)
        cvt_kernel<<<(2*DI*DM)/256, 256, 0, stream>>>(inw, (bf16*)inw_b, 2*DI*DM);
        cvt_kernel<<<(80*DI)/256, 256, 0, stream>>>(xwl, (bf16*)xw_b, 80*DI);
        cvt_kernel<<<(DM*DI)/256, 256, 0, stream>>>(owl, (bf16*)ow_b, DM*DI);

        rmsnorm_kernel<<<MTOK, 256, 0, stream>>>(h, norm_w + (size_t)l * DM, xn, nullptr);

        // xin = xn @ in_w[0:1536]^T   (MFMA)
        mgemm<0,0><<<dim3(DI/BN, MTOK/BM), 256, 0, stream>>>(
            (const short*)xn, DM, inw_b, DM, xy, DI, MTOK, DI, DM, nullptr, nullptr);

        // dbc = silu(conv(xin)) @ xw^T   (MFMA, conv fused into A staging)
        mgemm<0,1><<<dim3(1, MTOK/BM), 256, 0, stream>>>(
            (const short*)xy, DI, xw_b, DI, dbc, 80, MTOK, 80, DI, cwl, cbl);

        // chunked scan: pass1 -> combine -> pass2 (y overwrites xin in xy)
        scan_pass_kernel<1><<<scan_grid, 256, 0, stream>>>(
            xy, dbc, All, Dpl, dwl, dbl, cwl, cbl, hst, Ssum, bound);
        scan_combine_kernel<<<(NBATCH*DI*DS)/256, 256, 0, stream>>>(hst, Ssum, All);
        scan_pass_kernel<2><<<scan_grid, 256, 0, stream>>>(
            xy, dbc, All, Dpl, dwl, dbl, cwl, cbl, hst, Ssum, bound);

        // gating: y *= silu(xn @ in_w[1536:3072]^T)   (MFMA)
        mgemm<3,0><<<dim3(DI/BN, MTOK/BM), 256, 0, stream>>>(
            (const short*)xn, DM, inw_b + (size_t)DI*DM, DM, xy, DI, MTOK, DI, DM, nullptr, nullptr);

        // h += y @ out_w^T   (MFMA)
        mgemm<2,0><<<dim3(DM/BN, MTOK/BM), 256, 0, stream>>>(
            (const short*)xy, DI, ow_b, DI, h, DM, MTOK, DM, DI, nullptr, nullptr);
    }

    rmsnorm_kernel<<<MTOK, 256, 0, stream>>>(h, normf_w, nullptr, rsb);
    pool_kernel<<<dim3(NBATCH, DM/128, LSEQ/128), 128, 0, stream>>>(h, rsb, normf_w, pooled);
    head_kernel<<<1, 128, 0, stream>>>(pooled, cls_w, cls_b, labels, out);
}

// Round 7
// 1318.369 us; speedup vs baseline: 13.3826x; 1.0825x over previous
//
#include <hip/hip_runtime.h>
#include <hip/hip_bf16.h>
#include <math.h>

#define MTOK 16384      // B*L tokens
#define DM   768
#define DI   1536
#define DS   16
#define RNK  48
#define LSEQ 2048
#define NBATCH 8
#define EPSV 1e-5f
#define CHK  16         // time chunks for the scan
#define CLEN (LSEQ / CHK)
#define BM 128
#define BN 128
#define BK 32
#define KSPLIT 8        // split-K factor for the x_proj GEMM
#define EPS_STRIDE 72   // epilogue LDS row stride (shorts), 16B-aligned, conflict-light

typedef __hip_bfloat16 bf16;
typedef __attribute__((ext_vector_type(8))) short short8;
typedef __attribute__((ext_vector_type(4))) float floatx4;

__device__ __forceinline__ float b2f(bf16 v){ return __bfloat162float(v); }
__device__ __forceinline__ bf16  f2b(float v){ return __float2bfloat16(v); }
__device__ __forceinline__ float u2f(unsigned short u){
    union { unsigned int i; float f; } v; v.i = ((unsigned int)u) << 16; return v.f;
}
__device__ __forceinline__ float silu_f(float x){
    return x * __builtin_amdgcn_rcpf(1.f + __expf(-x));
}
__device__ __forceinline__ void gload_lds16(const void* g, void* l) {
    __builtin_amdgcn_global_load_lds(
        (const __attribute__((address_space(1))) void*)g,
        (__attribute__((address_space(3))) void*)l, 16, 0, 0);
}

// ---------------- fp32 -> bf16 convert ----------------
__global__ __launch_bounds__(256) void cvt_kernel(
    const float* __restrict__ x, bf16* __restrict__ h, int n)
{
    int i = blockIdx.x * 256 + threadIdx.x;
    if (i < n) h[i] = f2b(x[i]);
}

// ---------------- RMSNorm over 768 (3 elems/thread) ----------------
__global__ __launch_bounds__(256) void rmsnorm_kernel(
    const bf16* __restrict__ in, const float* __restrict__ w,
    bf16* __restrict__ out, float* __restrict__ rs_out)
{
    int row = blockIdx.x;
    const bf16* r = in + (size_t)row * DM;
    float v0 = b2f(r[threadIdx.x]);
    float v1 = b2f(r[threadIdx.x + 256]);
    float v2 = b2f(r[threadIdx.x + 512]);
    float s = v0*v0 + v1*v1 + v2*v2;
    for (int o = 32; o > 0; o >>= 1) s += __shfl_down(s, o, 64);
    __shared__ float red[4];
    if ((threadIdx.x & 63) == 0) red[threadIdx.x >> 6] = s;
    __syncthreads();
    float rs = rsqrtf((red[0]+red[1]+red[2]+red[3]) * (1.f/DM) + EPSV);
    if (rs_out && threadIdx.x == 0) rs_out[row] = rs;
    if (out) {
        out[(size_t)row*DM + threadIdx.x]       = f2b(v0 * rs * w[threadIdx.x]);
        out[(size_t)row*DM + threadIdx.x + 256] = f2b(v1 * rs * w[threadIdx.x + 256]);
        out[(size_t)row*DM + threadIdx.x + 512] = f2b(v2 * rs * w[threadIdx.x + 512]);
    }
}

// ---------------- bf16 MFMA GEMM: C[M,N] (op)= A[M,K] @ W[N,K]^T ----------------
// 128x128 tile, BK=32, 4 waves 2x2, each wave 4x4 mfma_f32_16x16x32_bf16.
// XOR-swizzled LDS tiles, wide-store epilogue via per-wave LDS bounce.
// MODE 0: C = acc ; MODE 2: C += acc ; MODE 3: C = C * silu(acc)
// MODE 4: atomicAdd fp32 partial into (float*)C  (split-K path, blockIdx.z)
// CONVA=1: A-tile = silu(causal dwconv4(A)) computed on the fly (x_proj path)
template<int MODE, int CONVA>
__global__ __launch_bounds__(256) void mgemm(
    const short* __restrict__ A, int lda,
    const short* __restrict__ W, int ldw,
    bf16* __restrict__ C, int ldc,
    int M, int N, int K,
    const float* __restrict__ cw, const float* __restrict__ cb,
    int ksteps_per_split)
{
    __shared__ __attribute__((aligned(16))) short As[BM*BK];
    __shared__ __attribute__((aligned(16))) short Bs[BN*BK];
    const int bm = blockIdx.y * BM;
    const int bn = blockIdx.x * BN;
    const int tid = threadIdx.x;
    const int wave = tid >> 6;
    const int lane = tid & 63;
    const int wm = (wave & 1) * 64;
    const int wn = (wave >> 1) * 64;
    const int r15 = lane & 15;
    const int quad = lane >> 4;

    int kbeg = 0, kend = K;
    if (MODE == 4) {
        kbeg = blockIdx.z * ksteps_per_split * BK;
        kend = kbeg + ksteps_per_split * BK;
        if (kend > K) kend = K;
    }

    const int srow = wave*32 + (lane >> 2);
    // XOR-swizzled staging column-chunk (chunk ^ localrow&3); row&3 == (lane>>2)&3
    const int swz = (lane & 3) ^ ((lane >> 2) & 3);
    int wr0 = bn + srow;      if (wr0 >= N) wr0 = N - 1;
    int wr1 = bn + srow + 16; if (wr1 >= N) wr1 = N - 1;

    floatx4 acc[4][4];
    const floatx4 zero = {0.f, 0.f, 0.f, 0.f};
    #pragma unroll
    for (int i = 0; i < 4; i++)
        #pragma unroll
        for (int j = 0; j < 4; j++) acc[i][j] = zero;

    const int kk = tid & 31;    // CONVA: column within A-tile
    const int tg = tid >> 5;    // CONVA: row group (16 rows)
    // fragment-read swizzle: A unswizzled when CONVA (ds_write staging)
    const int sA = CONVA ? quad : (quad ^ (r15 & 3));
    const int sB = quad ^ (r15 & 3);

    for (int k0 = kbeg; k0 < kend; k0 += BK) {
        if (CONVA) {
            int e = k0 + kk;
            float c0 = cw[e*4+0], c1 = cw[e*4+1], c2 = cw[e*4+2], c3 = cw[e*4+3];
            float cbe = cb[e];
            int g0 = bm + tg*16;
            const unsigned short* xp = (const unsigned short*)A + (size_t)g0 * lda + e;
            float p0 = 0.f, p1 = 0.f, p2 = 0.f;
            if ((g0 & (LSEQ-1)) != 0) {
                p0 = u2f(xp[-(ptrdiff_t)3*lda]);
                p1 = u2f(xp[-(ptrdiff_t)2*lda]);
                p2 = u2f(xp[-(ptrdiff_t)1*lda]);
            }
            #pragma unroll
            for (int i = 0; i < 16; i++) {
                float xt = u2f(xp[(size_t)i * lda]);
                float xv = silu_f(cbe + c0*p0 + c1*p1 + c2*p2 + c3*xt);
                p0 = p1; p1 = p2; p2 = xt;
                bf16 t = f2b(xv);
                As[(tg*16 + i)*BK + kk] = *(short*)&t;
            }
        } else {
            gload_lds16(A + (size_t)(bm + srow)      * lda + k0 + swz*8, &As[(wave*32)*BK]);
            gload_lds16(A + (size_t)(bm + srow + 16) * lda + k0 + swz*8, &As[(wave*32 + 16)*BK]);
        }
        gload_lds16(W + (size_t)wr0 * ldw + k0 + swz*8, &Bs[(wave*32)*BK]);
        gload_lds16(W + (size_t)wr1 * ldw + k0 + swz*8, &Bs[(wave*32 + 16)*BK]);
        __syncthreads();

        short8 af[4], bfr[4];
        #pragma unroll
        for (int i = 0; i < 4; i++) af[i]  = *(const short8*)&As[(wm + i*16 + r15)*BK + sA*8];
        #pragma unroll
        for (int i = 0; i < 4; i++) bfr[i] = *(const short8*)&Bs[(wn + i*16 + r15)*BK + sB*8];
        #pragma unroll
        for (int mt = 0; mt < 4; mt++)
            #pragma unroll
            for (int nt = 0; nt < 4; nt++)
                acc[mt][nt] = __builtin_amdgcn_mfma_f32_16x16x32_bf16(
                    af[mt], bfr[nt], acc[mt][nt], 0, 0, 0);
        __syncthreads();
    }

    if (MODE == 4) {
        // split-K partial: fp32 atomic accumulate, D row = quad*4+reg, col = r15
        float* Cf = (float*)C;
        #pragma unroll
        for (int nt = 0; nt < 4; nt++) {
            int n = bn + wn + nt*16 + r15;
            if (n >= N) continue;
            #pragma unroll
            for (int mt = 0; mt < 4; mt++)
                #pragma unroll
                for (int reg = 0; reg < 4; reg++) {
                    int m = bm + wm + mt*16 + quad*4 + reg;
                    atomicAdd(&Cf[(size_t)m * ldc + n], acc[mt][nt][reg]);
                }
        }
        return;
    }

    // ---- wide-store epilogue: bounce each wave's 64x64 tile through LDS ----
    short* ep = ((wave & 2) ? Bs : As) + (wave & 1) * 1152;
    const int lr = lane >> 2;
    const int lc = lane & 3;
    #pragma unroll
    for (int mt = 0; mt < 4; mt++) {
        #pragma unroll
        for (int nt = 0; nt < 4; nt++)
            #pragma unroll
            for (int reg = 0; reg < 4; reg++) {
                bf16 t = f2b(acc[mt][nt][reg]);
                ep[(quad*4 + reg)*EPS_STRIDE + nt*16 + r15] = *(short*)&t;
            }
        // read back row-major: lane -> row lr, 16-col chunk lc (32 B)
        short8 v0 = *(const short8*)&ep[lr*EPS_STRIDE + lc*16];
        short8 v1 = *(const short8*)&ep[lr*EPS_STRIDE + lc*16 + 8];
        int gm = bm + wm + mt*16 + lr;
        int gn = bn + wn + lc*16;
        if (gn < N) {
            bf16* cp = C + (size_t)gm * ldc + gn;
            if (MODE == 0) {
                *(short8*)cp       = v0;
                *(short8*)(cp + 8) = v1;
            } else {
                short8 c0 = *(const short8*)cp;
                short8 c1 = *(const short8*)(cp + 8);
                short8 o0, o1;
                #pragma unroll
                for (int j = 0; j < 8; j++) {
                    float cv0 = u2f((unsigned short)c0[j]);
                    float av0 = u2f((unsigned short)v0[j]);
                    float cv1 = u2f((unsigned short)c1[j]);
                    float av1 = u2f((unsigned short)v1[j]);
                    float r0 = (MODE == 2) ? (cv0 + av0) : (cv0 * silu_f(av0));
                    float r1 = (MODE == 2) ? (cv1 + av1) : (cv1 * silu_f(av1));
                    bf16 t0 = f2b(r0), t1 = f2b(r1);
                    o0[j] = *(short*)&t0;
                    o1[j] = *(short*)&t1;
                }
                *(short8*)cp       = o0;
                *(short8*)(cp + 8) = o1;
            }
        }
    }
}

// ---------------- chunked selective scan, no shuffles ----------------
template<int PASS>
__global__ __launch_bounds__(256) void scan_pass_kernel(
    bf16* __restrict__ xy,              // [M,1536]  xin (PASS2: y overwrites)
    const bf16* __restrict__ dbc,       // [M,80]  dt_r | B | C
    const float* __restrict__ A_log,    // [1536,16] layer slice
    const float* __restrict__ Dp,       // [1536]
    const float* __restrict__ dtw,      // [1536,48]
    const float* __restrict__ dtb,      // [1536]
    const float* __restrict__ cw,       // [1536,4]
    const float* __restrict__ cb,       // [1536]
    float* __restrict__ hst,            // [B*DI, CHK, 16]
    float* __restrict__ Ssum,           // [B*DI, CHK]
    unsigned short* __restrict__ bound) // [B*DI, CHK, 4]
{
    int e = (blockIdx.x % (DI/256)) * 256 + threadIdx.x;
    int b = (blockIdx.x / (DI/256)) & (NBATCH - 1);
    int c = blockIdx.x / ((DI/256) * NBATCH);
    int t0 = c * CLEN;

    float w[RNK];
    #pragma unroll
    for (int r = 0; r < RNK; r++) w[r] = dtw[e*RNK + r];
    float a[DS];
    #pragma unroll
    for (int n = 0; n < DS; n++) a[n] = -__expf(A_log[e*DS + n]);
    float c0 = cw[e*4+0], c1 = cw[e*4+1], c2 = cw[e*4+2], c3 = cw[e*4+3];
    float cbe = cb[e], dtbe = dtb[e], dpe = Dp[e];

    size_t sidx = ((size_t)(b*DI) + e) * CHK + c;
    float hh[DS];
    if (PASS == 1) {
        #pragma unroll
        for (int n = 0; n < DS; n++) hh[n] = 0.f;
    } else {
        #pragma unroll
        for (int n = 0; n < DS; n++) hh[n] = hst[sidx*DS + n];
    }

    unsigned short* xrow = (unsigned short*)(xy + ((size_t)(b*LSEQ) + t0) * DI + e);
    const unsigned short* drow = (const unsigned short*)(dbc + ((size_t)(b*LSEQ) + t0) * 80);

    unsigned short r0, r1, r2;
    if (PASS == 1) {
        if (c == 0) { r0 = 0; r1 = 0; r2 = 0; }
        else {
            r0 = xrow[-(ptrdiff_t)3*DI];
            r1 = xrow[-(ptrdiff_t)2*DI];
            r2 = xrow[-(ptrdiff_t)1*DI];
        }
        bound[sidx*4+0] = r0; bound[sidx*4+1] = r1; bound[sidx*4+2] = r2;
    } else {
        r0 = bound[sidx*4+0]; r1 = bound[sidx*4+1]; r2 = bound[sidx*4+2];
    }
    float p0 = u2f(r0), p1 = u2f(r1), p2 = u2f(r2);

    float S = 0.f;
    for (int t = 0; t < CLEN; t++) {
        float xt = u2f(xrow[(size_t)t * DI]);
        float xv = silu_f(cbe + c0*p0 + c1*p1 + c2*p2 + c3*xt);
        p0 = p1; p1 = p2; p2 = xt;

        uint4 q[5];
        const uint4* d4 = (const uint4*)(drow + (size_t)t * 80);
        #pragma unroll
        for (int i = 0; i < 5; i++) q[i] = d4[i];
        uint4 q2[5];
        #pragma unroll
        for (int i = 0; i < 5; i++) q2[i] = d4[5 + i];
        const unsigned short* ds = (const unsigned short*)q;
        const unsigned short* ds2 = (const unsigned short*)q2;

        float acc = dtbe;
        #pragma unroll
        for (int r = 0; r < RNK; r++) acc += w[r] * u2f(ds[r]);
        float d = (acc > 20.f) ? acc : __logf(1.f + __expf(acc));
        float dx = d * xv;
        #pragma unroll
        for (int n = 0; n < DS; n++)
            hh[n] = __expf(d * a[n]) * hh[n] + dx * u2f(ds[RNK + n]);

        if (PASS == 1) {
            S += d;
        } else {
            float y = xv * dpe;
            #pragma unroll
            for (int n = 0; n < DS; n++) y += hh[n] * u2f(ds2[n]);
            bf16 yb = f2b(y);
            xrow[(size_t)t * DI] = *(unsigned short*)&yb;
        }
    }
    if (PASS == 1) {
        #pragma unroll
        for (int n = 0; n < DS; n++) hst[sidx*DS + n] = hh[n];
        Ssum[sidx] = S;
    }
}

// ---------------- combine chunk states ----------------
__global__ __launch_bounds__(256) void scan_combine_kernel(
    float* __restrict__ hst, const float* __restrict__ Ssum,
    const float* __restrict__ A_log)
{
    int tid = blockIdx.x * 256 + threadIdx.x;
    int n = tid & 15;
    int bee = tid >> 4;
    int e = bee % DI;
    float a = -__expf(A_log[e*DS + n]);
    float run = 0.f;
    for (int c = 0; c < CHK; c++) {
        size_t idx = ((size_t)bee * CHK + c) * DS + n;
        float tmp = hst[idx];
        hst[idx] = run;
        run = tmp + __expf(a * Ssum[(size_t)bee*CHK + c]) * run;
    }
}

// ---------------- pooled[b,d] = (1/L) sum_t h[b,t,d]*rs[b,t]*wf[d] ----------------
__global__ __launch_bounds__(128) void pool_kernel(
    const bf16* __restrict__ h, const float* __restrict__ rs,
    const float* __restrict__ wf, float* __restrict__ pooled)
{
    int b = blockIdx.x, dc = blockIdx.y, tc = blockIdx.z;
    int d = dc * 128 + threadIdx.x;
    float s = 0.f;
    int t0 = tc * 128;
    for (int t = t0; t < t0 + 128; t++) {
        int row = b * LSEQ + t;
        s += b2f(h[(size_t)row * DM + d]) * rs[row];
    }
    atomicAdd(&pooled[b * DM + d], s * wf[d] * (1.f / LSEQ));
}

// ---------------- classifier head + log_softmax + NLL ----------------
__global__ __launch_bounds__(128) void head_kernel(
    const float* __restrict__ pooled, const float* __restrict__ cls_w,
    const float* __restrict__ cls_b, const int* __restrict__ labels,
    float* __restrict__ out)
{
    __shared__ float lg[80];
    int tid = threadIdx.x;
    if (tid < 80) {
        int b = tid / 10, c = tid % 10;
        float s = cls_b[c];
        for (int d = 0; d < DM; d++) s += pooled[b * DM + d] * cls_w[c * DM + d];
        lg[tid] = s;
    }
    __syncthreads();
    if (tid == 0) {
        float loss = 0.f;
        for (int b = 0; b < NBATCH; b++) {
            float mx = -1e30f;
            for (int c = 0; c < 10; c++) mx = fmaxf(mx, lg[b*10+c]);
            float se = 0.f;
            for (int c = 0; c < 10; c++) se += expf(lg[b*10+c] - mx);
            float lse = mx + logf(se);
            loss -= (lg[b*10 + labels[b]] - lse);
            for (int c = 0; c < 10; c++) out[b*10+c] = lg[b*10+c];
        }
        out[80] = loss / NBATCH;
    }
}

extern "C" void kernel_launch(void* const* d_in, const int* in_sizes, int n_in,
                              void* d_out, int out_size, void* d_ws, size_t ws_size,
                              hipStream_t stream) {
    const float* x          = (const float*)d_in[0];
    const int*   labels     = (const int*)d_in[1];
    const float* in_proj_w  = (const float*)d_in[2];
    const float* conv_w     = (const float*)d_in[3];
    const float* conv_b     = (const float*)d_in[4];
    const float* x_proj_w   = (const float*)d_in[5];
    const float* dt_w       = (const float*)d_in[6];
    const float* dt_b       = (const float*)d_in[7];
    const float* A_log      = (const float*)d_in[8];
    const float* D_param    = (const float*)d_in[9];
    const float* out_proj_w = (const float*)d_in[10];
    const float* norm_w     = (const float*)d_in[11];
    const float* normf_w    = (const float*)d_in[12];
    const float* cls_w      = (const float*)d_in[13];
    const float* cls_b      = (const float*)d_in[14];
    float* out = (float*)d_out;

    // workspace layout (~127 MB total)
    char* p = (char*)d_ws;
    bf16* h   = (bf16*)p;                 p += (size_t)MTOK * DM * 2;        // 25.2 MB
    bf16* xn  = (bf16*)p;                 p += (size_t)MTOK * DM * 2;        // 25.2 MB
    bf16* xy  = (bf16*)p;                 p += (size_t)MTOK * DI * 2;        // 50.3 MB (xin -> y)
    bf16* dbc = (bf16*)p;                 p += (size_t)MTOK * 80 * 2;        // 2.6 MB
    float* dbcf = (float*)p;              p += (size_t)MTOK * 80 * 4;        // 5.2 MB (split-K fp32 acc)
    float* hst = (float*)p;               p += (size_t)NBATCH*DI*CHK*DS*4;   // 12.6 MB
    float* Ssum = (float*)p;              p += (size_t)NBATCH*DI*CHK*4;      // 0.8 MB
    unsigned short* bound = (unsigned short*)p; p += (size_t)NBATCH*DI*CHK*4*2; // 1.6 MB
    float* rsb    = (float*)p;            p += (size_t)MTOK * 4;
    float* pooled = (float*)p;            p += NBATCH * DM * 4;
    short* inw_b = (short*)p;             p += (size_t)2*DI*DM * 2;          // 4.7 MB (per-layer)
    short* xw_b  = (short*)p;             p += (size_t)80*DI * 2;            // 0.25 MB
    short* ow_b  = (short*)p;             p += (size_t)DM*DI * 2;            // 2.4 MB

    cvt_kernel<<<(MTOK * DM) / 256, 256, 0, stream>>>(x, h, MTOK * DM);
    hipMemsetAsync(pooled, 0, NBATCH * DM * sizeof(float), stream);

    int scan_grid = (DI/256) * NBATCH * CHK;   // 768

    for (int l = 0; l < 4; l++) {
        const float* inw = in_proj_w + (size_t)l * 2 * DI * DM;
        const float* cwl = conv_w + (size_t)l * DI * 4;
        const float* cbl = conv_b + (size_t)l * DI;
        const float* xwl = x_proj_w + (size_t)l * (RNK + 2*DS) * DI;
        const float* dwl = dt_w + (size_t)l * DI * RNK;
        const float* dbl = dt_b + (size_t)l * DI;
        const float* All = A_log + (size_t)l * DI * DS;
        const float* Dpl = D_param + (size_t)l * DI;
        const float* owl = out_proj_w + (size_t)l * DM * DI;

        // per-layer weight conversion fp32 -> bf16 (reused buffers)
        cvt_kernel<<<(2*DI*DM)/256, 256, 0, stream>>>(inw, (bf16*)inw_b, 2*DI*DM);
        cvt_kernel<<<(80*DI)/256, 256, 0, stream>>>(xwl, (bf16*)xw_b, 80*DI);
        cvt_kernel<<<(DM*DI)/256, 256, 0, stream>>>(owl, (bf16*)ow_b, DM*DI);

        rmsnorm_kernel<<<MTOK, 256, 0, stream>>>(h, norm_w + (size_t)l * DM, xn, nullptr);

        // zero split-K accumulator (ws is re-poisoned 0xAA before every call)
        hipMemsetAsync(dbcf, 0, (size_t)MTOK * 80 * sizeof(float), stream);

        // xin = xn @ in_w[0:1536]^T   (MFMA)
        mgemm<0,0><<<dim3(DI/BN, MTOK/BM), 256, 0, stream>>>(
            (const short*)xn, DM, inw_b, DM, xy, DI, MTOK, DI, DM, nullptr, nullptr, 0);

        // dbc partials = silu(conv(xin)) @ xw^T   (MFMA split-K, conv fused)
        mgemm<4,1><<<dim3(1, MTOK/BM, KSPLIT), 256, 0, stream>>>(
            (const short*)xy, DI, xw_b, DI, (bf16*)dbcf, 80, MTOK, 80, DI,
            cwl, cbl, (DI/BK)/KSPLIT);
        cvt_kernel<<<(MTOK*80)/256, 256, 0, stream>>>(dbcf, dbc, MTOK*80);

        // chunked scan: pass1 -> combine -> pass2 (y overwrites xin in xy)
        scan_pass_kernel<1><<<scan_grid, 256, 0, stream>>>(
            xy, dbc, All, Dpl, dwl, dbl, cwl, cbl, hst, Ssum, bound);
        scan_combine_kernel<<<(NBATCH*DI*DS)/256, 256, 0, stream>>>(hst, Ssum, All);
        scan_pass_kernel<2><<<scan_grid, 256, 0, stream>>>(
            xy, dbc, All, Dpl, dwl, dbl, cwl, cbl, hst, Ssum, bound);

        // gating: y *= silu(xn @ in_w[1536:3072]^T)   (MFMA)
        mgemm<3,0><<<dim3(DI/BN, MTOK/BM), 256, 0, stream>>>(
            (const short*)xn, DM, inw_b + (size_t)DI*DM, DM, xy, DI, MTOK, DI, DM,
            nullptr, nullptr, 0);

        // h += y @ out_w^T   (MFMA)
        mgemm<2,0><<<dim3(DM/BN, MTOK/BM), 256, 0, stream>>>(
            (const short*)xy, DI, ow_b, DI, h, DM, MTOK, DM, DI, nullptr, nullptr, 0);
    }

    rmsnorm_kernel<<<MTOK, 256, 0, stream>>>(h, normf_w, nullptr, rsb);
    pool_kernel<<<dim3(NBATCH, DM/128, LSEQ/128), 128, 0, stream>>>(h, rsb, normf_w, pooled);
    head_kernel<<<1, 128, 0, stream>>>(pooled, cls_w, cls_b, labels, out);
}